// Round 10
// baseline (351.659 us; speedup 1.0000x reference)
//
#include <hip/hip_runtime.h>

// Problem constants
#define NPAR   8192      // parents
#define NCH    65536     // children = NPAR*8
#define RES    32
#define EPS    1e-5f

typedef __attribute__((ext_vector_type(8))) short short8;
typedef __attribute__((ext_vector_type(4))) float floatx4;

__device__ __forceinline__ unsigned short f2bf(float f) {
    union { float f; unsigned u; } v; v.f = f;
    unsigned r = v.u + 0x7fffu + ((v.u >> 16) & 1u);   // RNE
    return (unsigned short)(r >> 16);
}
__device__ __forceinline__ float bf2f(unsigned short b) {
    union { unsigned u; float f; } v; v.u = ((unsigned)b) << 16;
    return v.f;
}

// ---------------------------------------------------------------------------
// scatter parents into 32^3 grid (0xAA poison reads negative -> idx pass's
// bounds check rejects untouched cells). Zeroes stats[128] + zero page (512B).
__global__ void scatter_kernel(const int* __restrict__ coords, int* __restrict__ grid32,
                               float* __restrict__ stats, float* __restrict__ zpage) {
    int t = threadIdx.x;
    if (blockIdx.x == 0) {
        if (t < 128) stats[t] = 0.0f;
        else zpage[t - 128] = 0.0f;   // 128 floats = 512 B
    }
    int p = blockIdx.x * 256 + t;
    if (p < NPAR)
        grid32[(coords[p*3] << 10) + (coords[p*3+1] << 5) + coords[p*3+2]] = p;
}

// ---------------------------------------------------------------------------
// Fused prep: blocks [0,256) build idx_tab; blocks [256,688) pack weights.
// idx_tab[k][R] = input child-row for child R at tap k, or -1.
// Wp[tap][nb][ks][lane][j]: fragment-order bf16 weights (lane-linear 1KB loads).
__global__ void prep_kernel(const int* __restrict__ coords, const int* __restrict__ grid32,
                            int* __restrict__ idx_tab,
                            const float* __restrict__ W1, const float* __restrict__ W2,
                            unsigned short* __restrict__ Wp1, unsigned short* __restrict__ Wp2) {
    if (blockIdx.x < 256) {
        int R = blockIdx.x * 256 + threadIdx.x;   // 65536
        int p = R >> 3, o = R & 7;
        int bx = 2 * coords[p*3]   + ((o >> 2) & 1);
        int by = 2 * coords[p*3+1] + ((o >> 1) & 1);
        int bz = 2 * coords[p*3+2] + (o & 1);
#pragma unroll 1
        for (int k = 0; k < 27; ++k) {
            int fx = bx + k / 9 - 1, fy = by + (k / 3) % 3 - 1, fz = bz + k % 3 - 1;
            int src = -1;
            if ((unsigned)fx < 64u && (unsigned)fy < 64u && (unsigned)fz < 64u) {
                int r = grid32[((fx >> 1) << 10) + ((fy >> 1) << 5) + (fz >> 1)];
                if ((unsigned)r < (unsigned)NPAR)
                    src = r * 8 + ((fx & 1) << 2) + ((fy & 1) << 1) + (fz & 1);
            }
            idx_tab[k * NCH + R] = src;
        }
    } else {
        int idx = (blockIdx.x - 256) * 256 + threadIdx.x;   // < 110592
        int which = idx >= 55296 ? 1 : 0;
        int rem = idx - which * 55296;
        int lane = rem & 63;
        int ks   = (rem >> 6) & 3;
        int nb   = (rem >> 8) & 7;
        int tap  = rem >> 11;
        int n  = nb * 16 + (lane & 15);
        int k0 = ks * 32 + (lane >> 4) * 8;
        const float* W = which ? W2 : W1;
        unsigned short* Wp = which ? Wp2 : Wp1;
        unsigned short v[8];
#pragma unroll
        for (int j = 0; j < 8; ++j) v[j] = f2bf(W[tap * 16384 + (k0 + j) * 128 + n]);
        uint4 pk;
        pk.x = (unsigned)v[0] | ((unsigned)v[1] << 16);
        pk.y = (unsigned)v[2] | ((unsigned)v[3] << 16);
        pk.z = (unsigned)v[4] | ((unsigned)v[5] << 16);
        pk.w = (unsigned)v[6] | ((unsigned)v[7] << 16);
        *(uint4*)&Wp[(long)rem * 8] = pk;
    }
}

// ---------------------------------------------------------------------------
__global__ void gn_stats_kernel(const float* __restrict__ x, float* __restrict__ sum,
                                float* __restrict__ sq, int nrows) {
    __shared__ float s_sum[32], s_sq[32];
    int t = threadIdx.x;
    if (t < 32) { s_sum[t] = 0.0f; s_sq[t] = 0.0f; }
    __syncthreads();
    const float4* x4 = (const float4*)x;
    int total = nrows * 32;
    int idx0 = blockIdx.x * blockDim.x + t;
    int g = idx0 & 31;
    float ls = 0.0f, lq = 0.0f;
    for (int idx = idx0; idx < total; idx += gridDim.x * blockDim.x) {
        float4 v = x4[idx];
        ls += v.x + v.y + v.z + v.w;
        lq += v.x * v.x + v.y * v.y + v.z * v.z + v.w * v.w;
    }
    atomicAdd(&s_sum[g], ls);
    atomicAdd(&s_sq[g], lq);
    __syncthreads();
    if (t < 32) { atomicAdd(&sum[t], s_sum[t]); atomicAdd(&sq[t], s_sq[t]); }
}

// fp32 in -> bf16 out (GN1)
__global__ void gn_apply_kernel(const float* __restrict__ x, const float* __restrict__ sum,
                                const float* __restrict__ sq, const float* __restrict__ gamma,
                                const float* __restrict__ beta, unsigned short* __restrict__ y,
                                int nrows) {
    const float4* x4 = (const float4*)x;
    uint2* y2 = (uint2*)y;
    const float4* g4 = (const float4*)gamma;
    const float4* b4 = (const float4*)beta;
    float cnt = (float)nrows * 4.0f;
    int total = nrows * 32;
    for (int idx = blockIdx.x * blockDim.x + threadIdx.x; idx < total;
         idx += gridDim.x * blockDim.x) {
        int c4 = idx & 31;
        float mean = sum[c4] / cnt;
        float var = sq[c4] / cnt - mean * mean;
        float rstd = rsqrtf(var + EPS);
        float4 v = x4[idx];
        float4 gm = g4[c4];
        float4 bt = b4[c4];
        float a[4] = {v.x, v.y, v.z, v.w};
        float gg[4] = {gm.x, gm.y, gm.z, gm.w};
        float bb[4] = {bt.x, bt.y, bt.z, bt.w};
        unsigned short o[4];
#pragma unroll
        for (int i = 0; i < 4; ++i) {
            float tv = (a[i] - mean) * rstd * gg[i] + bb[i];
            o[i] = f2bf(tv / (1.0f + __expf(-tv)));
        }
        uint2 pk;
        pk.x = (unsigned)o[0] | ((unsigned)o[1] << 16);
        pk.y = (unsigned)o[2] | ((unsigned)o[3] << 16);
        y2[idx] = pk;
    }
}

// bf16 in -> bf16 out, in place (GN2)
__global__ void gn_apply_bf16_kernel(unsigned short* __restrict__ x,
                                     const float* __restrict__ sum, const float* __restrict__ sq,
                                     const float* __restrict__ gamma, const float* __restrict__ beta,
                                     int nrows) {
    uint2* x2 = (uint2*)x;
    const float4* g4 = (const float4*)gamma;
    const float4* b4 = (const float4*)beta;
    float cnt = (float)nrows * 4.0f;
    int total = nrows * 32;
    for (int idx = blockIdx.x * blockDim.x + threadIdx.x; idx < total;
         idx += gridDim.x * blockDim.x) {
        int c4 = idx & 31;
        float mean = sum[c4] / cnt;
        float var = sq[c4] / cnt - mean * mean;
        float rstd = rsqrtf(var + EPS);
        uint2 pk = x2[idx];
        float a[4] = {bf2f((unsigned short)(pk.x & 0xffff)), bf2f((unsigned short)(pk.x >> 16)),
                      bf2f((unsigned short)(pk.y & 0xffff)), bf2f((unsigned short)(pk.y >> 16))};
        float4 gm = g4[c4];
        float4 bt = b4[c4];
        float gg[4] = {gm.x, gm.y, gm.z, gm.w};
        float bb[4] = {bt.x, bt.y, bt.z, bt.w};
        unsigned short o[4];
#pragma unroll
        for (int i = 0; i < 4; ++i) {
            float tv = (a[i] - mean) * rstd * gg[i] + bb[i];
            o[i] = f2bf(tv / (1.0f + __expf(-tv)));
        }
        pk.x = (unsigned)o[0] | ((unsigned)o[1] << 16);
        pk.y = (unsigned)o[2] | ((unsigned)o[3] << 16);
        x2[idx] = pk;
    }
}

// ---------------------------------------------------------------------------
// MFMA conv v6 — BARRIER-FREE. Block = 64 rows, 128 threads = 2 waves; wave
// wv computes all 64 rows x cols [wv*64,+64). NO LDS staging: the MFMA
// A-fragment (row=mt*16+l16, k=ks*32+quad*8+j) is loaded DIRECTLY from global
// as a per-lane 16B read (same 16-lines/instr footprint as the old DMA, minus
// the LDS round-trip and minus the per-tap __syncthreads vmcnt(0) drain that
// serialized r7-r9 at ~85 µs). Loads from many ks-slices stay in flight with
// fine-grained vmcnt. Invalid rows -> per-lane select of a zeroed 512B page.
// Row indices for tap k+1 prefetched during tap k. B-frags from packed Wp
// (lane-linear 1KB, L1-hot). Occupancy now VGPR-bound: launch_bounds(128,3).
__global__ void __launch_bounds__(128, 3) conv_mfma_kernel(
    const unsigned short* __restrict__ Ag, const unsigned short* __restrict__ Wp,
    const float* __restrict__ bias, const int* __restrict__ idx_tab,
    const float* __restrict__ resid, void* __restrict__ outp,
    const float* __restrict__ zpage, int shift, int out_bf16,
    float* __restrict__ gsum, float* __restrict__ gsq) {
    __shared__ float sred[64];

    int t = threadIdx.x;
    int R0 = blockIdx.x * 64;
    int wv = t >> 6, lane = t & 63, quad = lane >> 4, l16 = lane & 15;
    const unsigned short* zsrc = (const unsigned short*)zpage;
    const int* ip = idx_tab + R0 + l16;   // per-lane idx base (lanes share per l16)

    floatx4 acc[4][4];
#pragma unroll
    for (int mt = 0; mt < 4; ++mt)
#pragma unroll
        for (int nt = 0; nt < 4; ++nt)
            acc[mt][nt] = (floatx4){0.f, 0.f, 0.f, 0.f};

    int idxv[4];
#pragma unroll
    for (int mt = 0; mt < 4; ++mt) idxv[mt] = ip[mt * 16];

#pragma unroll 1
    for (int k = 0; k < 27; ++k) {
        // per-lane A-frag base pointers for this tap (quad folded in)
        const unsigned short* ap[4];
#pragma unroll
        for (int mt = 0; mt < 4; ++mt)
            ap[mt] = ((idxv[mt] >= 0) ? Ag + (long)(idxv[mt] >> shift) * 128 : zsrc) + quad * 8;
        // prefetch next tap's indices (long pole: idx -> addr -> load -> mfma)
        if (k < 26) {
#pragma unroll
            for (int mt = 0; mt < 4; ++mt) idxv[mt] = ip[(k + 1) * NCH + mt * 16];
        }
        // dense 64x64x128 wave GEMM, ks-sliced register buffering
#pragma unroll
        for (int ks = 0; ks < 4; ++ks) {
            short8 afr[4], bfr[4];
#pragma unroll
            for (int mt = 0; mt < 4; ++mt)
                afr[mt] = *(const short8*)(ap[mt] + ks * 32);
#pragma unroll
            for (int nt = 0; nt < 4; ++nt) {
                int cb = wv * 4 + nt;
                bfr[nt] = *(const short8*)&Wp[((((k << 3) + cb) << 2) + ks) * 512 + (lane << 3)];
            }
#pragma unroll
            for (int mt = 0; mt < 4; ++mt)
#pragma unroll
                for (int nt = 0; nt < 4; ++nt)
                    acc[mt][nt] = __builtin_amdgcn_mfma_f32_16x16x32_bf16(
                        afr[mt], bfr[nt], acc[mt][nt], 0, 0, 0);
        }
    }

    // ---- epilogue
    float s[4] = {0.f, 0.f, 0.f, 0.f}, q[4] = {0.f, 0.f, 0.f, 0.f};
#pragma unroll
    for (int nt = 0; nt < 4; ++nt) {
        int col = wv * 64 + nt * 16 + l16;
        float bv = bias[col];
#pragma unroll
        for (int mt = 0; mt < 4; ++mt) {
#pragma unroll
            for (int r = 0; r < 4; ++r) {
                int row = mt * 16 + quad * 4 + r;
                long R = (long)R0 + row;
                float v = acc[mt][nt][r] + bv;
                if (out_bf16) {
                    unsigned short u = f2bf(v);
                    ((unsigned short*)outp)[R * 128 + col] = u;
                    float vr = bf2f(u);
                    s[nt] += vr;
                    q[nt] += vr * vr;
                } else {
                    v += resid[(R >> 3) * 128 + col];
                    ((float*)outp)[R * 128 + col] = v;
                }
            }
        }
    }
    if (gsum) {
        if (t < 64) sred[t] = 0.0f;
        __syncthreads();
#pragma unroll
        for (int nt = 0; nt < 4; ++nt) {
            int g = (wv * 64 + nt * 16 + l16) >> 2;
            atomicAdd(&sred[g], s[nt]);
            atomicAdd(&sred[32 + g], q[nt]);
        }
        __syncthreads();
        if (t < 32) { atomicAdd(&gsum[t], sred[t]); atomicAdd(&gsq[t], sred[32 + t]); }
    }
}

// ---------------------------------------------------------------------------
extern "C" void kernel_launch(void* const* d_in, const int* in_sizes, int n_in,
                              void* d_out, int out_size, void* d_ws, size_t ws_size,
                              hipStream_t stream) {
    const float* feats  = (const float*)d_in[0];
    const float* gamma1 = (const float*)d_in[1];
    const float* beta1  = (const float*)d_in[2];
    const float* W1     = (const float*)d_in[3];
    const float* b1     = (const float*)d_in[4];
    const float* gamma2 = (const float*)d_in[5];
    const float* beta2  = (const float*)d_in[6];
    const float* W2     = (const float*)d_in[7];
    const float* b2     = (const float*)d_in[8];
    const int*   coords = (const int*)d_in[9];
    float* out = (float*)d_out;   // 65536 x 128 fp32 (written only by conv2)

    char* ws = (char*)d_ws;
    unsigned short* h0b = (unsigned short*)(ws);                    // 2 MB
    unsigned short* h1b = (unsigned short*)(ws + (2u << 20));       // 16 MB
    unsigned short* Wp1 = (unsigned short*)(ws + (18u << 20));      // 864 KB
    unsigned short* Wp2 = (unsigned short*)(ws + (19u << 20));      // 864 KB
    int*   grid32       = (int*)  (ws + (20u << 20));               // 128 KB
    float* stats        = (float*)(ws + (20u << 20) + 131072);      // 512 B
    float* zpage        = (float*)(ws + (20u << 20) + 131072 + 512);// 512 B
    int*   idx_tab      = (int*)  (ws + (21u << 20));               // 7.08 MB

    scatter_kernel<<<NPAR / 256, 256, 0, stream>>>(coords, grid32, stats, zpage);
    prep_kernel<<<688, 256, 0, stream>>>(coords, grid32, idx_tab, W1, W2, Wp1, Wp2);

    gn_stats_kernel<<<256, 256, 0, stream>>>(feats, stats + 0, stats + 32, NPAR);
    gn_apply_kernel<<<256, 256, 0, stream>>>(feats, stats + 0, stats + 32, gamma1, beta1, h0b, NPAR);

    // conv1 -> bf16 h1b (+fused GN2 stats on rounded values)
    conv_mfma_kernel<<<NCH / 64, 128, 0, stream>>>(h0b, Wp1, b1, idx_tab,
                                                   nullptr, h1b, zpage, 3, 1,
                                                   stats + 64, stats + 96);

    gn_apply_bf16_kernel<<<512, 256, 0, stream>>>(h1b, stats + 64, stats + 96, gamma2, beta2, NCH);

    // conv2 -> fp32 out + residual repeat(feats,8)
    conv_mfma_kernel<<<NCH / 64, 128, 0, stream>>>(h1b, Wp2, b2, idx_tab,
                                                   feats, out, zpage, 0, 0,
                                                   nullptr, nullptr);
}

// Round 11
// 214.877 us; speedup vs baseline: 1.6366x; 1.6366x over previous
//
#include <hip/hip_runtime.h>

// Problem constants
#define NPAR   8192      // parents
#define NCH    65536     // children = NPAR*8
#define RES    32
#define EPS    1e-5f

typedef __attribute__((ext_vector_type(8))) short short8;
typedef __attribute__((ext_vector_type(4))) float floatx4;

__device__ __forceinline__ unsigned short f2bf(float f) {
    union { float f; unsigned u; } v; v.f = f;
    unsigned r = v.u + 0x7fffu + ((v.u >> 16) & 1u);   // RNE
    return (unsigned short)(r >> 16);
}
__device__ __forceinline__ float bf2f(unsigned short b) {
    union { unsigned u; float f; } v; v.u = ((unsigned)b) << 16;
    return v.f;
}
// async 16B global->LDS: per-lane global addr, wave-uniform LDS base (+lane*16)
__device__ __forceinline__ void glds16(const void* g, void* l) {
    __builtin_amdgcn_global_load_lds(
        (__attribute__((address_space(1))) const void*)g,
        (__attribute__((address_space(3))) void*)l, 16, 0, 0);
}
// parent-grid tap index for (child-offset o, slot s): e_a = o_a + s_a - 1
__device__ __forceinline__ int k27_of(int o, int s) {
    return (((o >> 2) & 1) + ((s >> 2) & 1)) * 9 +
           (((o >> 1) & 1) + ((s >> 1) & 1)) * 3 +
           ((o & 1) + (s & 1));
}
// fine-tap d-list per axis for (o,s) folding
__device__ __forceinline__ void axis_dlist(int o, int s, int* d, int& n) {
    if (o == 0) { if (s == 0) { d[0] = -1; n = 1; } else { d[0] = 0; d[1] = 1; n = 2; } }
    else        { if (s == 0) { d[0] = -1; d[1] = 0; n = 2; } else { d[0] = 1; n = 1; } }
}

// ---------------------------------------------------------------------------
// scatter parents into 32^3 grid (0xAA poison reads negative -> table builders'
// bounds checks reject untouched cells). Zeroes stats[128] + zero page (512B).
__global__ void scatter_kernel(const int* __restrict__ coords, int* __restrict__ grid32,
                               float* __restrict__ stats, float* __restrict__ zpage) {
    int t = threadIdx.x;
    if (blockIdx.x == 0) {
        if (t < 128) stats[t] = 0.0f;
        else zpage[t - 128] = 0.0f;   // 128 floats = 512 B
    }
    int p = blockIdx.x * 256 + t;
    if (p < NPAR)
        grid32[(coords[p*3] << 10) + (coords[p*3+1] << 5) + coords[p*3+2]] = p;
}

// ---------------------------------------------------------------------------
// Fused prep, 1848 blocks:
//  [0,256)     child idx_tab[k][R] (conv2 gather table)
//  [256,472)   pack W2 -> Wp2[tap][nb][ks][lane][8] (fragment order)
//  [472,984)   fold W1 per (o,s) + pack -> Wc1f[o*8+s][nb][ks][lane][8]
//  [984,1848)  parent 27-neighbor table pidx27[k][p]
__global__ void prep_kernel(const int* __restrict__ coords, const int* __restrict__ grid32,
                            int* __restrict__ idx_tab, int* __restrict__ pidx27,
                            const float* __restrict__ W1, const float* __restrict__ W2,
                            unsigned short* __restrict__ Wc1f, unsigned short* __restrict__ Wp2) {
    int b = blockIdx.x;
    if (b < 256) {
        int R = b * 256 + threadIdx.x;   // 65536
        int p = R >> 3, o = R & 7;
        int bx = 2 * coords[p*3]   + ((o >> 2) & 1);
        int by = 2 * coords[p*3+1] + ((o >> 1) & 1);
        int bz = 2 * coords[p*3+2] + (o & 1);
#pragma unroll 1
        for (int k = 0; k < 27; ++k) {
            int fx = bx + k / 9 - 1, fy = by + (k / 3) % 3 - 1, fz = bz + k % 3 - 1;
            int src = -1;
            if ((unsigned)fx < 64u && (unsigned)fy < 64u && (unsigned)fz < 64u) {
                int r = grid32[((fx >> 1) << 10) + ((fy >> 1) << 5) + (fz >> 1)];
                if ((unsigned)r < (unsigned)NPAR)
                    src = r * 8 + ((fx & 1) << 2) + ((fy & 1) << 1) + (fz & 1);
            }
            idx_tab[k * NCH + R] = src;
        }
    } else if (b < 472) {
        int rem = (b - 256) * 256 + threadIdx.x;   // < 55296
        int lane = rem & 63;
        int ks   = (rem >> 6) & 3;
        int nb   = (rem >> 8) & 7;
        int tap  = rem >> 11;                       // 0..26
        int n  = nb * 16 + (lane & 15);
        int k0 = ks * 32 + (lane >> 4) * 8;
        unsigned short v[8];
#pragma unroll
        for (int j = 0; j < 8; ++j) v[j] = f2bf(W2[tap * 16384 + (k0 + j) * 128 + n]);
        uint4 pk;
        pk.x = (unsigned)v[0] | ((unsigned)v[1] << 16);
        pk.y = (unsigned)v[2] | ((unsigned)v[3] << 16);
        pk.z = (unsigned)v[4] | ((unsigned)v[5] << 16);
        pk.w = (unsigned)v[6] | ((unsigned)v[7] << 16);
        *(uint4*)&Wp2[(long)rem * 8] = pk;
    } else if (b < 984) {
        int rem = (b - 472) * 256 + threadIdx.x;   // < 131072
        int lane  = rem & 63;
        int ks    = (rem >> 6) & 3;
        int nb    = (rem >> 8) & 7;
        int combo = rem >> 11;                      // 0..63 = o*8+s
        int o = combo >> 3, s = combo & 7;
        int n  = nb * 16 + (lane & 15);
        int k0 = ks * 32 + (lane >> 4) * 8;
        int d0[2], d1[2], d2[2], n0, n1, n2;
        axis_dlist((o >> 2) & 1, (s >> 2) & 1, d0, n0);
        axis_dlist((o >> 1) & 1, (s >> 1) & 1, d1, n1);
        axis_dlist(o & 1,        s & 1,        d2, n2);
        unsigned short v[8];
#pragma unroll
        for (int j = 0; j < 8; ++j) {
            float acc = 0.0f;
            for (int a = 0; a < n0; ++a)
                for (int bb = 0; bb < n1; ++bb)
                    for (int cc = 0; cc < n2; ++cc) {
                        int kk = (d0[a] + 1) * 9 + (d1[bb] + 1) * 3 + (d2[cc] + 1);
                        acc += W1[kk * 16384 + (k0 + j) * 128 + n];
                    }
            v[j] = f2bf(acc);
        }
        uint4 pk;
        pk.x = (unsigned)v[0] | ((unsigned)v[1] << 16);
        pk.y = (unsigned)v[2] | ((unsigned)v[3] << 16);
        pk.z = (unsigned)v[4] | ((unsigned)v[5] << 16);
        pk.w = (unsigned)v[6] | ((unsigned)v[7] << 16);
        *(uint4*)&Wc1f[(long)rem * 8] = pk;
    } else {
        int gid = (b - 984) * 256 + threadIdx.x;   // < 221184 = 27*8192
        int k = gid >> 13, p = gid & 8191;
        int nx = coords[p*3]   + k / 9 - 1;
        int ny = coords[p*3+1] + (k / 3) % 3 - 1;
        int nz = coords[p*3+2] + k % 3 - 1;
        int src = -1;
        if ((unsigned)nx < 32u && (unsigned)ny < 32u && (unsigned)nz < 32u) {
            int r = grid32[(nx << 10) + (ny << 5) + nz];
            if ((unsigned)r < (unsigned)NPAR) src = r;
        }
        pidx27[k * NPAR + p] = src;
    }
}

// ---------------------------------------------------------------------------
__global__ void gn_stats_kernel(const float* __restrict__ x, float* __restrict__ sum,
                                float* __restrict__ sq, int nrows) {
    __shared__ float s_sum[32], s_sq[32];
    int t = threadIdx.x;
    if (t < 32) { s_sum[t] = 0.0f; s_sq[t] = 0.0f; }
    __syncthreads();
    const float4* x4 = (const float4*)x;
    int total = nrows * 32;
    int idx0 = blockIdx.x * blockDim.x + t;
    int g = idx0 & 31;
    float ls = 0.0f, lq = 0.0f;
    for (int idx = idx0; idx < total; idx += gridDim.x * blockDim.x) {
        float4 v = x4[idx];
        ls += v.x + v.y + v.z + v.w;
        lq += v.x * v.x + v.y * v.y + v.z * v.z + v.w * v.w;
    }
    atomicAdd(&s_sum[g], ls);
    atomicAdd(&s_sq[g], lq);
    __syncthreads();
    if (t < 32) { atomicAdd(&sum[t], s_sum[t]); atomicAdd(&sq[t], s_sq[t]); }
}

// fp32 in -> bf16 out (GN1)
__global__ void gn_apply_kernel(const float* __restrict__ x, const float* __restrict__ sum,
                                const float* __restrict__ sq, const float* __restrict__ gamma,
                                const float* __restrict__ beta, unsigned short* __restrict__ y,
                                int nrows) {
    const float4* x4 = (const float4*)x;
    uint2* y2 = (uint2*)y;
    const float4* g4 = (const float4*)gamma;
    const float4* b4 = (const float4*)beta;
    float cnt = (float)nrows * 4.0f;
    int total = nrows * 32;
    for (int idx = blockIdx.x * blockDim.x + threadIdx.x; idx < total;
         idx += gridDim.x * blockDim.x) {
        int c4 = idx & 31;
        float mean = sum[c4] / cnt;
        float var = sq[c4] / cnt - mean * mean;
        float rstd = rsqrtf(var + EPS);
        float4 v = x4[idx];
        float4 gm = g4[c4];
        float4 bt = b4[c4];
        float a[4] = {v.x, v.y, v.z, v.w};
        float gg[4] = {gm.x, gm.y, gm.z, gm.w};
        float bb[4] = {bt.x, bt.y, bt.z, bt.w};
        unsigned short o[4];
#pragma unroll
        for (int i = 0; i < 4; ++i) {
            float tv = (a[i] - mean) * rstd * gg[i] + bb[i];
            o[i] = f2bf(tv / (1.0f + __expf(-tv)));
        }
        uint2 pk;
        pk.x = (unsigned)o[0] | ((unsigned)o[1] << 16);
        pk.y = (unsigned)o[2] | ((unsigned)o[3] << 16);
        y2[idx] = pk;
    }
}

// bf16 in -> bf16 out, in place (GN2)
__global__ void gn_apply_bf16_kernel(unsigned short* __restrict__ x,
                                     const float* __restrict__ sum, const float* __restrict__ sq,
                                     const float* __restrict__ gamma, const float* __restrict__ beta,
                                     int nrows) {
    uint2* x2 = (uint2*)x;
    const float4* g4 = (const float4*)gamma;
    const float4* b4 = (const float4*)beta;
    float cnt = (float)nrows * 4.0f;
    int total = nrows * 32;
    for (int idx = blockIdx.x * blockDim.x + threadIdx.x; idx < total;
         idx += gridDim.x * blockDim.x) {
        int c4 = idx & 31;
        float mean = sum[c4] / cnt;
        float var = sq[c4] / cnt - mean * mean;
        float rstd = rsqrtf(var + EPS);
        uint2 pk = x2[idx];
        float a[4] = {bf2f((unsigned short)(pk.x & 0xffff)), bf2f((unsigned short)(pk.x >> 16)),
                      bf2f((unsigned short)(pk.y & 0xffff)), bf2f((unsigned short)(pk.y >> 16))};
        float4 gm = g4[c4];
        float4 bt = b4[c4];
        float gg[4] = {gm.x, gm.y, gm.z, gm.w};
        float bb[4] = {bt.x, bt.y, bt.z, bt.w};
        unsigned short o[4];
#pragma unroll
        for (int i = 0; i < 4; ++i) {
            float tv = (a[i] - mean) * rstd * gg[i] + bb[i];
            o[i] = f2bf(tv / (1.0f + __expf(-tv)));
        }
        pk.x = (unsigned)o[0] | ((unsigned)o[1] << 16);
        pk.y = (unsigned)o[2] | ((unsigned)o[3] << 16);
        x2[idx] = pk;
    }
}

// ---------------------------------------------------------------------------
// CONV1 FOLDED (r8 v4 structure, 8 slot-taps over PARENT rows):
// block = (o, 128 parents), 256 threads = 4 waves (2x2). Per slot s: gather
// 128 parent rows of h0 via async glds (fragment-order LDS, dbuf 2x32KB),
// B = folded Wc1f[o*8+s] (packed, lane-linear). Epilogue: child row p*8+o,
// bf16 store + fused GN2 stats on rounded values.
__global__ void __launch_bounds__(256) conv1_fold_kernel(
    const unsigned short* __restrict__ Ag, const unsigned short* __restrict__ Wc1f,
    const float* __restrict__ bias, const int* __restrict__ pidx27,
    unsigned short* __restrict__ outp, const float* __restrict__ zpage,
    float* __restrict__ gsum, float* __restrict__ gsq) {
    __shared__ unsigned short A_lds[2][16384];   // 2 x 32 KB

    int t = threadIdx.x;
    int o  = blockIdx.x & 7;
    int P0 = (blockIdx.x >> 3) << 7;            // 128 parents per block
    const unsigned short* Wb = Wc1f + ((long)o << 17);   // o*8*16384
    int wv = t >> 6, lane = t & 63, quad = lane >> 4, l16 = lane & 15;
    int wm = wv & 1, wn = wv >> 1;
    int r16 = lane >> 2, cch = lane & 3;
    int c0 = wv * 2, c1 = wv * 2 + 1;
    int row0 = ((c0 >> 2) << 6) + ((c0 & 3) << 4) + r16;
    int row1 = ((c1 >> 2) << 6) + ((c1 & 3) << 4) + r16;
    int base0 = ((c0 >> 2) << 13) + ((c0 & 3) << 11);
    int base1 = ((c1 >> 2) << 13) + ((c1 & 3) << 11);
    const unsigned short* zsrc = (const unsigned short*)zpage;

    floatx4 acc[4][4];
#pragma unroll
    for (int mt = 0; mt < 4; ++mt)
#pragma unroll
        for (int nt = 0; nt < 4; ++nt)
            acc[mt][nt] = (floatx4){0.f, 0.f, 0.f, 0.f};

    // ---- prolog: slot 0 into buf 0
    int iv0 = pidx27[k27_of(o, 0) * NPAR + P0 + row0];
    int iv1 = pidx27[k27_of(o, 0) * NPAR + P0 + row1];
    {
        const unsigned short* g0 = (iv0 >= 0) ? Ag + (long)iv0 * 128 : zsrc;
        const unsigned short* g1 = (iv1 >= 0) ? Ag + (long)iv1 * 128 : zsrc;
#pragma unroll
        for (int i = 0; i < 4; ++i) glds16(g0 + i * 32 + cch * 8, &A_lds[0][base0 + i * 512]);
#pragma unroll
        for (int i = 0; i < 4; ++i) glds16(g1 + i * 32 + cch * 8, &A_lds[0][base1 + i * 512]);
    }
    int nv0 = pidx27[k27_of(o, 1) * NPAR + P0 + row0];
    int nv1 = pidx27[k27_of(o, 1) * NPAR + P0 + row1];
    __syncthreads();

#pragma unroll 1
    for (int s = 0; s < 8; ++s) {
        int cur = s & 1;
        if (s < 7) {
            const unsigned short* g0 = (nv0 >= 0) ? Ag + (long)nv0 * 128 : zsrc;
            const unsigned short* g1 = (nv1 >= 0) ? Ag + (long)nv1 * 128 : zsrc;
#pragma unroll
            for (int i = 0; i < 4; ++i) glds16(g0 + i * 32 + cch * 8, &A_lds[1 - cur][base0 + i * 512]);
#pragma unroll
            for (int i = 0; i < 4; ++i) glds16(g1 + i * 32 + cch * 8, &A_lds[1 - cur][base1 + i * 512]);
            if (s < 6) {
                nv0 = pidx27[k27_of(o, s + 2) * NPAR + P0 + row0];
                nv1 = pidx27[k27_of(o, s + 2) * NPAR + P0 + row1];
            }
        }
#pragma unroll
        for (int ks = 0; ks < 4; ++ks) {
            short8 afr[4], bfr[4];
#pragma unroll
            for (int mt = 0; mt < 4; ++mt)
                afr[mt] = *(const short8*)&A_lds[cur][(wm << 13) + (mt << 11) + (ks << 9) + (l16 << 5) + (quad << 3)];
#pragma unroll
            for (int nt = 0; nt < 4; ++nt) {
                int cb = wn * 4 + nt;
                bfr[nt] = *(const short8*)&Wb[((((s << 3) + cb) << 2) + ks) * 512 + (lane << 3)];
            }
#pragma unroll
            for (int mt = 0; mt < 4; ++mt)
#pragma unroll
                for (int nt = 0; nt < 4; ++nt)
                    acc[mt][nt] = __builtin_amdgcn_mfma_f32_16x16x32_bf16(
                        afr[mt], bfr[nt], acc[mt][nt], 0, 0, 0);
        }
        __syncthreads();
    }

    // ---- epilogue: bf16 store at child rows p*8+o, fused GN2 stats
    float s_[4] = {0.f, 0.f, 0.f, 0.f}, q_[4] = {0.f, 0.f, 0.f, 0.f};
#pragma unroll
    for (int nt = 0; nt < 4; ++nt) {
        int col = wn * 64 + nt * 16 + l16;
        float bv = bias[col];
#pragma unroll
        for (int mt = 0; mt < 4; ++mt) {
#pragma unroll
            for (int r = 0; r < 4; ++r) {
                int prow = wm * 64 + mt * 16 + quad * 4 + r;
                long R = ((long)(P0 + prow) << 3) + o;
                float v = acc[mt][nt][r] + bv;
                unsigned short u = f2bf(v);
                outp[R * 128 + col] = u;
                float vr = bf2f(u);
                s_[nt] += vr;
                q_[nt] += vr * vr;
            }
        }
    }
    float* sred = (float*)A_lds;   // safe: loop's trailing barrier passed
    if (t < 64) sred[t] = 0.0f;
    __syncthreads();
#pragma unroll
    for (int nt = 0; nt < 4; ++nt) {
        int g = (wn * 64 + nt * 16 + l16) >> 2;
        atomicAdd(&sred[g], s_[nt]);
        atomicAdd(&sred[32 + g], q_[nt]);
    }
    __syncthreads();
    if (t < 32) { atomicAdd(&gsum[t], sred[t]); atomicAdd(&gsq[t], sred[32 + t]); }
}

// ---------------------------------------------------------------------------
// CONV2 — exact r8 v4 structure (82 µs measured): block = 128 child rows,
// 256 threads = 4 waves (2x2), 27 taps, dbuf glds staging, fp32 out + residual.
__global__ void __launch_bounds__(256) conv2_kernel(
    const unsigned short* __restrict__ Ag, const unsigned short* __restrict__ Wp,
    const float* __restrict__ bias, const int* __restrict__ idx_tab,
    const float* __restrict__ resid, float* __restrict__ outp,
    const float* __restrict__ zpage) {
    __shared__ unsigned short A_lds[2][16384];   // 2 x 32 KB

    int t = threadIdx.x;
    int R0 = blockIdx.x * 128;
    int wv = t >> 6, lane = t & 63, quad = lane >> 4, l16 = lane & 15;
    int wm = wv & 1, wn = wv >> 1;
    int r16 = lane >> 2, cch = lane & 3;
    int c0 = wv * 2, c1 = wv * 2 + 1;
    int row0 = ((c0 >> 2) << 6) + ((c0 & 3) << 4) + r16;
    int row1 = ((c1 >> 2) << 6) + ((c1 & 3) << 4) + r16;
    int base0 = ((c0 >> 2) << 13) + ((c0 & 3) << 11);
    int base1 = ((c1 >> 2) << 13) + ((c1 & 3) << 11);
    const unsigned short* zsrc = (const unsigned short*)zpage;

    floatx4 acc[4][4];
#pragma unroll
    for (int mt = 0; mt < 4; ++mt)
#pragma unroll
        for (int nt = 0; nt < 4; ++nt)
            acc[mt][nt] = (floatx4){0.f, 0.f, 0.f, 0.f};

    int iv0 = idx_tab[R0 + row0], iv1 = idx_tab[R0 + row1];
    {
        const unsigned short* g0 = (iv0 >= 0) ? Ag + (long)iv0 * 128 : zsrc;
        const unsigned short* g1 = (iv1 >= 0) ? Ag + (long)iv1 * 128 : zsrc;
#pragma unroll
        for (int i = 0; i < 4; ++i) glds16(g0 + i * 32 + cch * 8, &A_lds[0][base0 + i * 512]);
#pragma unroll
        for (int i = 0; i < 4; ++i) glds16(g1 + i * 32 + cch * 8, &A_lds[0][base1 + i * 512]);
    }
    int nv0 = idx_tab[NCH + R0 + row0], nv1 = idx_tab[NCH + R0 + row1];
    __syncthreads();

#pragma unroll 1
    for (int k = 0; k < 27; ++k) {
        int cur = k & 1;
        if (k < 26) {
            const unsigned short* g0 = (nv0 >= 0) ? Ag + (long)nv0 * 128 : zsrc;
            const unsigned short* g1 = (nv1 >= 0) ? Ag + (long)nv1 * 128 : zsrc;
#pragma unroll
            for (int i = 0; i < 4; ++i) glds16(g0 + i * 32 + cch * 8, &A_lds[1 - cur][base0 + i * 512]);
#pragma unroll
            for (int i = 0; i < 4; ++i) glds16(g1 + i * 32 + cch * 8, &A_lds[1 - cur][base1 + i * 512]);
            if (k < 25) {
                nv0 = idx_tab[(k + 2) * NCH + R0 + row0];
                nv1 = idx_tab[(k + 2) * NCH + R0 + row1];
            }
        }
#pragma unroll
        for (int ks = 0; ks < 4; ++ks) {
            short8 afr[4], bfr[4];
#pragma unroll
            for (int mt = 0; mt < 4; ++mt)
                afr[mt] = *(const short8*)&A_lds[cur][(wm << 13) + (mt << 11) + (ks << 9) + (l16 << 5) + (quad << 3)];
#pragma unroll
            for (int nt = 0; nt < 4; ++nt) {
                int cb = wn * 4 + nt;
                bfr[nt] = *(const short8*)&Wp[((((k << 3) + cb) << 2) + ks) * 512 + (lane << 3)];
            }
#pragma unroll
            for (int mt = 0; mt < 4; ++mt)
#pragma unroll
                for (int nt = 0; nt < 4; ++nt)
                    acc[mt][nt] = __builtin_amdgcn_mfma_f32_16x16x32_bf16(
                        afr[mt], bfr[nt], acc[mt][nt], 0, 0, 0);
        }
        __syncthreads();
    }

#pragma unroll
    for (int nt = 0; nt < 4; ++nt) {
        int col = wn * 64 + nt * 16 + l16;
        float bv = bias[col];
#pragma unroll
        for (int mt = 0; mt < 4; ++mt) {
#pragma unroll
            for (int r = 0; r < 4; ++r) {
                int row = wm * 64 + mt * 16 + quad * 4 + r;
                long R = (long)R0 + row;
                float v = acc[mt][nt][r] + bv + resid[(R >> 3) * 128 + col];
                outp[R * 128 + col] = v;
            }
        }
    }
}

// ---------------------------------------------------------------------------
extern "C" void kernel_launch(void* const* d_in, const int* in_sizes, int n_in,
                              void* d_out, int out_size, void* d_ws, size_t ws_size,
                              hipStream_t stream) {
    const float* feats  = (const float*)d_in[0];
    const float* gamma1 = (const float*)d_in[1];
    const float* beta1  = (const float*)d_in[2];
    const float* W1     = (const float*)d_in[3];
    const float* b1     = (const float*)d_in[4];
    const float* gamma2 = (const float*)d_in[5];
    const float* beta2  = (const float*)d_in[6];
    const float* W2     = (const float*)d_in[7];
    const float* b2     = (const float*)d_in[8];
    const int*   coords = (const int*)d_in[9];
    float* out = (float*)d_out;   // 65536 x 128 fp32 (written only by conv2)

    char* ws = (char*)d_ws;
    unsigned short* h0b  = (unsigned short*)(ws);                    // 2 MB
    unsigned short* h1b  = (unsigned short*)(ws + (2u << 20));       // 16 MB
    unsigned short* Wc1f = (unsigned short*)(ws + (18u << 20));      // 2 MB
    unsigned short* Wp2  = (unsigned short*)(ws + (20u << 20));      // 864 KB
    int*   grid32        = (int*)  (ws + (21u << 20));               // 128 KB
    float* stats         = (float*)(ws + (21u << 20) + 131072);      // 512 B
    float* zpage         = (float*)(ws + (21u << 20) + 131072 + 512);// 512 B
    int*   idx_tab       = (int*)  (ws + (22u << 20));               // 7.08 MB
    int*   pidx27        = (int*)  (ws + (30u << 20));               // 864 KB

    scatter_kernel<<<NPAR / 256, 256, 0, stream>>>(coords, grid32, stats, zpage);
    prep_kernel<<<1848, 256, 0, stream>>>(coords, grid32, idx_tab, pidx27,
                                          W1, W2, Wc1f, Wp2);

    gn_stats_kernel<<<256, 256, 0, stream>>>(feats, stats + 0, stats + 32, NPAR);
    gn_apply_kernel<<<256, 256, 0, stream>>>(feats, stats + 0, stats + 32, gamma1, beta1, h0b, NPAR);

    // conv1 folded (8 slots over parents) -> bf16 h1b + fused GN2 stats
    conv1_fold_kernel<<<8 * (NPAR / 128), 256, 0, stream>>>(h0b, Wc1f, b1, pidx27,
                                                            h1b, zpage,
                                                            stats + 64, stats + 96);

    gn_apply_bf16_kernel<<<512, 256, 0, stream>>>(h1b, stats + 64, stats + 96, gamma2, beta2, NCH);

    // conv2 (27 taps over children) -> fp32 out + residual repeat(feats,8)
    conv2_kernel<<<NCH / 128, 256, 0, stream>>>(h1b, Wp2, b2, idx_tab,
                                                feats, out, zpage);
}

// Round 12
// 211.743 us; speedup vs baseline: 1.6608x; 1.0148x over previous
//
#include <hip/hip_runtime.h>

// Problem constants
#define NPAR   8192      // parents
#define NCH    65536     // children = NPAR*8
#define RES    32
#define EPS    1e-5f

typedef __attribute__((ext_vector_type(8))) short short8;
typedef __attribute__((ext_vector_type(4))) float floatx4;

__device__ __forceinline__ unsigned short f2bf(float f) {
    union { float f; unsigned u; } v; v.f = f;
    unsigned r = v.u + 0x7fffu + ((v.u >> 16) & 1u);   // RNE
    return (unsigned short)(r >> 16);
}
__device__ __forceinline__ float bf2f(unsigned short b) {
    union { unsigned u; float f; } v; v.u = ((unsigned)b) << 16;
    return v.f;
}
// async 16B global->LDS: per-lane global addr, wave-uniform LDS base (+lane*16)
__device__ __forceinline__ void glds16(const void* g, void* l) {
    __builtin_amdgcn_global_load_lds(
        (__attribute__((address_space(1))) const void*)g,
        (__attribute__((address_space(3))) void*)l, 16, 0, 0);
}
// parent-grid tap index for (child-offset o, slot s): e_a = o_a + s_a - 1
__device__ __forceinline__ int k27_of(int o, int s) {
    return (((o >> 2) & 1) + ((s >> 2) & 1)) * 9 +
           (((o >> 1) & 1) + ((s >> 1) & 1)) * 3 +
           ((o & 1) + (s & 1));
}
// fine-tap d-list per axis for (o,s) folding
__device__ __forceinline__ void axis_dlist(int o, int s, int* d, int& n) {
    if (o == 0) { if (s == 0) { d[0] = -1; n = 1; } else { d[0] = 0; d[1] = 1; n = 2; } }
    else        { if (s == 0) { d[0] = -1; d[1] = 0; n = 2; } else { d[0] = 1; n = 1; } }
}

// ---------------------------------------------------------------------------
// K1: blocks [0,32) scatter parents into grid32; blocks [32,288) GN1 stats.
// stats/zpage pre-zeroed by hipMemsetAsync (no intra-kernel ordering hazard).
__global__ void k1_kernel(const int* __restrict__ coords, int* __restrict__ grid32,
                          const float* __restrict__ x, float* __restrict__ sum,
                          float* __restrict__ sq) {
    int b = blockIdx.x;
    int t = threadIdx.x;
    if (b < 32) {
        int p = b * 256 + t;
        grid32[(coords[p*3] << 10) + (coords[p*3+1] << 5) + coords[p*3+2]] = p;
    } else {
        __shared__ float s_sum[32], s_sq[32];
        if (t < 32) { s_sum[t] = 0.0f; s_sq[t] = 0.0f; }
        __syncthreads();
        const float4* x4 = (const float4*)x;
        int total = NPAR * 32;
        int idx0 = (b - 32) * 256 + t;
        int g = idx0 & 31;
        float ls = 0.0f, lq = 0.0f;
        for (int idx = idx0; idx < total; idx += 256 * 256) {
            float4 v = x4[idx];
            ls += v.x + v.y + v.z + v.w;
            lq += v.x * v.x + v.y * v.y + v.z * v.z + v.w * v.w;
        }
        atomicAdd(&s_sum[g], ls);
        atomicAdd(&s_sq[g], lq);
        __syncthreads();
        if (t < 32) { atomicAdd(&sum[t], s_sum[t]); atomicAdd(&sq[t], s_sq[t]); }
    }
}

// ---------------------------------------------------------------------------
// K2, 2104 blocks:
//  [0,256)      child idx_tab[k][R] -> (o,p)-layout row index c*NPAR+r, or -1
//  [256,472)    pack W2 -> Wp2[tap][nb][ks][lane][8] (fragment order)
//  [472,984)    fold W1 per (o,s) + pack -> Wc1f[o*8+s][nb][ks][lane][8]
//  [984,1848)   parent 27-neighbor table pidx27[k][p]
//  [1848,2104)  GN1 apply: feats -> bf16 h0b (reads stats from K1)
__global__ void k2_kernel(const int* __restrict__ coords, const int* __restrict__ grid32,
                          int* __restrict__ idx_tab, int* __restrict__ pidx27,
                          const float* __restrict__ W1, const float* __restrict__ W2,
                          unsigned short* __restrict__ Wc1f, unsigned short* __restrict__ Wp2,
                          const float* __restrict__ x, const float* __restrict__ sum,
                          const float* __restrict__ sq, const float* __restrict__ gamma,
                          const float* __restrict__ beta, unsigned short* __restrict__ y) {
    int b = blockIdx.x;
    if (b < 256) {
        int R = b * 256 + threadIdx.x;   // 65536
        int p = R >> 3, o = R & 7;
        int bx = 2 * coords[p*3]   + ((o >> 2) & 1);
        int by = 2 * coords[p*3+1] + ((o >> 1) & 1);
        int bz = 2 * coords[p*3+2] + (o & 1);
#pragma unroll 1
        for (int k = 0; k < 27; ++k) {
            int fx = bx + k / 9 - 1, fy = by + (k / 3) % 3 - 1, fz = bz + k % 3 - 1;
            int src = -1;
            if ((unsigned)fx < 64u && (unsigned)fy < 64u && (unsigned)fz < 64u) {
                int r = grid32[((fx >> 1) << 10) + ((fy >> 1) << 5) + (fz >> 1)];
                if ((unsigned)r < (unsigned)NPAR)
                    src = (((fx & 1) << 2) + ((fy & 1) << 1) + (fz & 1)) * NPAR + r;
            }
            idx_tab[k * NCH + R] = src;
        }
    } else if (b < 472) {
        int rem = (b - 256) * 256 + threadIdx.x;   // < 55296
        int lane = rem & 63;
        int ks   = (rem >> 6) & 3;
        int nb   = (rem >> 8) & 7;
        int tap  = rem >> 11;                       // 0..26
        int n  = nb * 16 + (lane & 15);
        int k0 = ks * 32 + (lane >> 4) * 8;
        unsigned short v[8];
#pragma unroll
        for (int j = 0; j < 8; ++j) v[j] = f2bf(W2[tap * 16384 + (k0 + j) * 128 + n]);
        uint4 pk;
        pk.x = (unsigned)v[0] | ((unsigned)v[1] << 16);
        pk.y = (unsigned)v[2] | ((unsigned)v[3] << 16);
        pk.z = (unsigned)v[4] | ((unsigned)v[5] << 16);
        pk.w = (unsigned)v[6] | ((unsigned)v[7] << 16);
        *(uint4*)&Wp2[(long)rem * 8] = pk;
    } else if (b < 984) {
        int rem = (b - 472) * 256 + threadIdx.x;   // < 131072
        int lane  = rem & 63;
        int ks    = (rem >> 6) & 3;
        int nb    = (rem >> 8) & 7;
        int combo = rem >> 11;                      // 0..63 = o*8+s
        int o = combo >> 3, s = combo & 7;
        int n  = nb * 16 + (lane & 15);
        int k0 = ks * 32 + (lane >> 4) * 8;
        int d0[2], d1[2], d2[2], n0, n1, n2;
        axis_dlist((o >> 2) & 1, (s >> 2) & 1, d0, n0);
        axis_dlist((o >> 1) & 1, (s >> 1) & 1, d1, n1);
        axis_dlist(o & 1,        s & 1,        d2, n2);
        unsigned short v[8];
#pragma unroll
        for (int j = 0; j < 8; ++j) {
            float acc = 0.0f;
            for (int a = 0; a < n0; ++a)
                for (int bb = 0; bb < n1; ++bb)
                    for (int cc = 0; cc < n2; ++cc) {
                        int kk = (d0[a] + 1) * 9 + (d1[bb] + 1) * 3 + (d2[cc] + 1);
                        acc += W1[kk * 16384 + (k0 + j) * 128 + n];
                    }
            v[j] = f2bf(acc);
        }
        uint4 pk;
        pk.x = (unsigned)v[0] | ((unsigned)v[1] << 16);
        pk.y = (unsigned)v[2] | ((unsigned)v[3] << 16);
        pk.z = (unsigned)v[4] | ((unsigned)v[5] << 16);
        pk.w = (unsigned)v[6] | ((unsigned)v[7] << 16);
        *(uint4*)&Wc1f[(long)rem * 8] = pk;
    } else if (b < 1848) {
        int gid = (b - 984) * 256 + threadIdx.x;   // < 221184 = 27*8192
        int k = gid >> 13, p = gid & 8191;
        int nx = coords[p*3]   + k / 9 - 1;
        int ny = coords[p*3+1] + (k / 3) % 3 - 1;
        int nz = coords[p*3+2] + k % 3 - 1;
        int src = -1;
        if ((unsigned)nx < 32u && (unsigned)ny < 32u && (unsigned)nz < 32u) {
            int r = grid32[(nx << 10) + (ny << 5) + nz];
            if ((unsigned)r < (unsigned)NPAR) src = r;
        }
        pidx27[k * NPAR + p] = src;
    } else {
        const float4* x4 = (const float4*)x;
        uint2* y2 = (uint2*)y;
        const float4* g4 = (const float4*)gamma;
        const float4* b4 = (const float4*)beta;
        float cnt = (float)NPAR * 4.0f;
        int total = NPAR * 32;
        for (int idx = (b - 1848) * 256 + threadIdx.x; idx < total; idx += 256 * 256) {
            int c4 = idx & 31;
            float mean = sum[c4] / cnt;
            float var = sq[c4] / cnt - mean * mean;
            float rstd = rsqrtf(var + EPS);
            float4 v = x4[idx];
            float4 gm = g4[c4];
            float4 bt = b4[c4];
            float a[4] = {v.x, v.y, v.z, v.w};
            float gg[4] = {gm.x, gm.y, gm.z, gm.w};
            float bb[4] = {bt.x, bt.y, bt.z, bt.w};
            unsigned short o[4];
#pragma unroll
            for (int i = 0; i < 4; ++i) {
                float tv = (a[i] - mean) * rstd * gg[i] + bb[i];
                o[i] = f2bf(tv / (1.0f + __expf(-tv)));
            }
            uint2 pk;
            pk.x = (unsigned)o[0] | ((unsigned)o[1] << 16);
            pk.y = (unsigned)o[2] | ((unsigned)o[3] << 16);
            y2[idx] = pk;
        }
    }
}

// ---------------------------------------------------------------------------
// bf16 in -> bf16 out, in place (GN2); layout-agnostic elementwise
__global__ void gn_apply_bf16_kernel(unsigned short* __restrict__ x,
                                     const float* __restrict__ sum, const float* __restrict__ sq,
                                     const float* __restrict__ gamma, const float* __restrict__ beta,
                                     int nrows) {
    uint2* x2 = (uint2*)x;
    const float4* g4 = (const float4*)gamma;
    const float4* b4 = (const float4*)beta;
    float cnt = (float)nrows * 4.0f;
    int total = nrows * 32;
    for (int idx = blockIdx.x * blockDim.x + threadIdx.x; idx < total;
         idx += gridDim.x * blockDim.x) {
        int c4 = idx & 31;
        float mean = sum[c4] / cnt;
        float var = sq[c4] / cnt - mean * mean;
        float rstd = rsqrtf(var + EPS);
        uint2 pk = x2[idx];
        float a[4] = {bf2f((unsigned short)(pk.x & 0xffff)), bf2f((unsigned short)(pk.x >> 16)),
                      bf2f((unsigned short)(pk.y & 0xffff)), bf2f((unsigned short)(pk.y >> 16))};
        float4 gm = g4[c4];
        float4 bt = b4[c4];
        float gg[4] = {gm.x, gm.y, gm.z, gm.w};
        float bb[4] = {bt.x, bt.y, bt.z, bt.w};
        unsigned short o[4];
#pragma unroll
        for (int i = 0; i < 4; ++i) {
            float tv = (a[i] - mean) * rstd * gg[i] + bb[i];
            o[i] = f2bf(tv / (1.0f + __expf(-tv)));
        }
        pk.x = (unsigned)o[0] | ((unsigned)o[1] << 16);
        pk.y = (unsigned)o[2] | ((unsigned)o[3] << 16);
        x2[idx] = pk;
    }
}

// ---------------------------------------------------------------------------
// CONV1 FOLDED: block = (o, 128 parents), 256 threads = 4 waves (2x2).
// Per slot s: gather 128 parent rows of h0 via async glds, B = Wc1f[o*8+s].
// h1 is in (o,p) LAYOUT: out row = o*NPAR + p -> epilogue stores are fully
// coalesced (contiguous parent rows), unlike the old p*8+o stride-8 scatter.
__global__ void __launch_bounds__(256) conv1_fold_kernel(
    const unsigned short* __restrict__ Ag, const unsigned short* __restrict__ Wc1f,
    const float* __restrict__ bias, const int* __restrict__ pidx27,
    unsigned short* __restrict__ outp, const float* __restrict__ zpage,
    float* __restrict__ gsum, float* __restrict__ gsq) {
    __shared__ unsigned short A_lds[2][16384];   // 2 x 32 KB

    int t = threadIdx.x;
    int o  = blockIdx.x & 7;
    int P0 = (blockIdx.x >> 3) << 7;            // 128 parents per block
    const unsigned short* Wb = Wc1f + ((long)o << 17);   // o*8*16384
    int wv = t >> 6, lane = t & 63, quad = lane >> 4, l16 = lane & 15;
    int wm = wv & 1, wn = wv >> 1;
    int r16 = lane >> 2, cch = lane & 3;
    int c0 = wv * 2, c1 = wv * 2 + 1;
    int row0 = ((c0 >> 2) << 6) + ((c0 & 3) << 4) + r16;
    int row1 = ((c1 >> 2) << 6) + ((c1 & 3) << 4) + r16;
    int base0 = ((c0 >> 2) << 13) + ((c0 & 3) << 11);
    int base1 = ((c1 >> 2) << 13) + ((c1 & 3) << 11);
    const unsigned short* zsrc = (const unsigned short*)zpage;

    floatx4 acc[4][4];
#pragma unroll
    for (int mt = 0; mt < 4; ++mt)
#pragma unroll
        for (int nt = 0; nt < 4; ++nt)
            acc[mt][nt] = (floatx4){0.f, 0.f, 0.f, 0.f};

    int iv0 = pidx27[k27_of(o, 0) * NPAR + P0 + row0];
    int iv1 = pidx27[k27_of(o, 0) * NPAR + P0 + row1];
    {
        const unsigned short* g0 = (iv0 >= 0) ? Ag + (long)iv0 * 128 : zsrc;
        const unsigned short* g1 = (iv1 >= 0) ? Ag + (long)iv1 * 128 : zsrc;
#pragma unroll
        for (int i = 0; i < 4; ++i) glds16(g0 + i * 32 + cch * 8, &A_lds[0][base0 + i * 512]);
#pragma unroll
        for (int i = 0; i < 4; ++i) glds16(g1 + i * 32 + cch * 8, &A_lds[0][base1 + i * 512]);
    }
    int nv0 = pidx27[k27_of(o, 1) * NPAR + P0 + row0];
    int nv1 = pidx27[k27_of(o, 1) * NPAR + P0 + row1];
    __syncthreads();

#pragma unroll 1
    for (int s = 0; s < 8; ++s) {
        int cur = s & 1;
        if (s < 7) {
            const unsigned short* g0 = (nv0 >= 0) ? Ag + (long)nv0 * 128 : zsrc;
            const unsigned short* g1 = (nv1 >= 0) ? Ag + (long)nv1 * 128 : zsrc;
#pragma unroll
            for (int i = 0; i < 4; ++i) glds16(g0 + i * 32 + cch * 8, &A_lds[1 - cur][base0 + i * 512]);
#pragma unroll
            for (int i = 0; i < 4; ++i) glds16(g1 + i * 32 + cch * 8, &A_lds[1 - cur][base1 + i * 512]);
            if (s < 6) {
                nv0 = pidx27[k27_of(o, s + 2) * NPAR + P0 + row0];
                nv1 = pidx27[k27_of(o, s + 2) * NPAR + P0 + row1];
            }
        }
#pragma unroll
        for (int ks = 0; ks < 4; ++ks) {
            short8 afr[4], bfr[4];
#pragma unroll
            for (int mt = 0; mt < 4; ++mt)
                afr[mt] = *(const short8*)&A_lds[cur][(wm << 13) + (mt << 11) + (ks << 9) + (l16 << 5) + (quad << 3)];
#pragma unroll
            for (int nt = 0; nt < 4; ++nt) {
                int cb = wn * 4 + nt;
                bfr[nt] = *(const short8*)&Wb[((((s << 3) + cb) << 2) + ks) * 512 + (lane << 3)];
            }
#pragma unroll
            for (int mt = 0; mt < 4; ++mt)
#pragma unroll
                for (int nt = 0; nt < 4; ++nt)
                    acc[mt][nt] = __builtin_amdgcn_mfma_f32_16x16x32_bf16(
                        afr[mt], bfr[nt], acc[mt][nt], 0, 0, 0);
        }
        __syncthreads();
    }

    // ---- epilogue: coalesced bf16 store at row o*NPAR + p, fused GN2 stats
    float s_[4] = {0.f, 0.f, 0.f, 0.f}, q_[4] = {0.f, 0.f, 0.f, 0.f};
#pragma unroll
    for (int nt = 0; nt < 4; ++nt) {
        int col = wn * 64 + nt * 16 + l16;
        float bv = bias[col];
#pragma unroll
        for (int mt = 0; mt < 4; ++mt) {
#pragma unroll
            for (int r = 0; r < 4; ++r) {
                int prow = wm * 64 + mt * 16 + quad * 4 + r;
                long R = (long)o * NPAR + P0 + prow;
                float v = acc[mt][nt][r] + bv;
                unsigned short u = f2bf(v);
                outp[R * 128 + col] = u;
                float vr = bf2f(u);
                s_[nt] += vr;
                q_[nt] += vr * vr;
            }
        }
    }
    float* sred = (float*)A_lds;   // safe: loop's trailing barrier passed
    if (t < 64) sred[t] = 0.0f;
    __syncthreads();
#pragma unroll
    for (int nt = 0; nt < 4; ++nt) {
        int g = (wn * 64 + nt * 16 + l16) >> 2;
        atomicAdd(&sred[g], s_[nt]);
        atomicAdd(&sred[32 + g], q_[nt]);
    }
    __syncthreads();
    if (t < 32) { atomicAdd(&gsum[t], sred[t]); atomicAdd(&gsq[t], sred[32 + t]); }
}

// ---------------------------------------------------------------------------
// CONV2 — r8/r11 structure (68 µs measured): block = 128 child rows,
// 256 threads = 4 waves (2x2), 27 taps, dbuf glds staging, fp32 out + residual.
// idx_tab entries now address h1's (o,p) layout; kernel body unchanged.
__global__ void __launch_bounds__(256) conv2_kernel(
    const unsigned short* __restrict__ Ag, const unsigned short* __restrict__ Wp,
    const float* __restrict__ bias, const int* __restrict__ idx_tab,
    const float* __restrict__ resid, float* __restrict__ outp,
    const float* __restrict__ zpage) {
    __shared__ unsigned short A_lds[2][16384];   // 2 x 32 KB

    int t = threadIdx.x;
    int R0 = blockIdx.x * 128;
    int wv = t >> 6, lane = t & 63, quad = lane >> 4, l16 = lane & 15;
    int wm = wv & 1, wn = wv >> 1;
    int r16 = lane >> 2, cch = lane & 3;
    int c0 = wv * 2, c1 = wv * 2 + 1;
    int row0 = ((c0 >> 2) << 6) + ((c0 & 3) << 4) + r16;
    int row1 = ((c1 >> 2) << 6) + ((c1 & 3) << 4) + r16;
    int base0 = ((c0 >> 2) << 13) + ((c0 & 3) << 11);
    int base1 = ((c1 >> 2) << 13) + ((c1 & 3) << 11);
    const unsigned short* zsrc = (const unsigned short*)zpage;

    floatx4 acc[4][4];
#pragma unroll
    for (int mt = 0; mt < 4; ++mt)
#pragma unroll
        for (int nt = 0; nt < 4; ++nt)
            acc[mt][nt] = (floatx4){0.f, 0.f, 0.f, 0.f};

    int iv0 = idx_tab[R0 + row0], iv1 = idx_tab[R0 + row1];
    {
        const unsigned short* g0 = (iv0 >= 0) ? Ag + (long)iv0 * 128 : zsrc;
        const unsigned short* g1 = (iv1 >= 0) ? Ag + (long)iv1 * 128 : zsrc;
#pragma unroll
        for (int i = 0; i < 4; ++i) glds16(g0 + i * 32 + cch * 8, &A_lds[0][base0 + i * 512]);
#pragma unroll
        for (int i = 0; i < 4; ++i) glds16(g1 + i * 32 + cch * 8, &A_lds[0][base1 + i * 512]);
    }
    int nv0 = idx_tab[NCH + R0 + row0], nv1 = idx_tab[NCH + R0 + row1];
    __syncthreads();

#pragma unroll 1
    for (int k = 0; k < 27; ++k) {
        int cur = k & 1;
        if (k < 26) {
            const unsigned short* g0 = (nv0 >= 0) ? Ag + (long)nv0 * 128 : zsrc;
            const unsigned short* g1 = (nv1 >= 0) ? Ag + (long)nv1 * 128 : zsrc;
#pragma unroll
            for (int i = 0; i < 4; ++i) glds16(g0 + i * 32 + cch * 8, &A_lds[1 - cur][base0 + i * 512]);
#pragma unroll
            for (int i = 0; i < 4; ++i) glds16(g1 + i * 32 + cch * 8, &A_lds[1 - cur][base1 + i * 512]);
            if (k < 25) {
                nv0 = idx_tab[(k + 2) * NCH + R0 + row0];
                nv1 = idx_tab[(k + 2) * NCH + R0 + row1];
            }
        }
#pragma unroll
        for (int ks = 0; ks < 4; ++ks) {
            short8 afr[4], bfr[4];
#pragma unroll
            for (int mt = 0; mt < 4; ++mt)
                afr[mt] = *(const short8*)&A_lds[cur][(wm << 13) + (mt << 11) + (ks << 9) + (l16 << 5) + (quad << 3)];
#pragma unroll
            for (int nt = 0; nt < 4; ++nt) {
                int cb = wn * 4 + nt;
                bfr[nt] = *(const short8*)&Wp[((((k << 3) + cb) << 2) + ks) * 512 + (lane << 3)];
            }
#pragma unroll
            for (int mt = 0; mt < 4; ++mt)
#pragma unroll
                for (int nt = 0; nt < 4; ++nt)
                    acc[mt][nt] = __builtin_amdgcn_mfma_f32_16x16x32_bf16(
                        afr[mt], bfr[nt], acc[mt][nt], 0, 0, 0);
        }
        __syncthreads();
    }

#pragma unroll
    for (int nt = 0; nt < 4; ++nt) {
        int col = wn * 64 + nt * 16 + l16;
        float bv = bias[col];
#pragma unroll
        for (int mt = 0; mt < 4; ++mt) {
#pragma unroll
            for (int r = 0; r < 4; ++r) {
                int row = wm * 64 + mt * 16 + quad * 4 + r;
                long R = (long)R0 + row;
                float v = acc[mt][nt][r] + bv + resid[(R >> 3) * 128 + col];
                outp[R * 128 + col] = v;
            }
        }
    }
}

// ---------------------------------------------------------------------------
extern "C" void kernel_launch(void* const* d_in, const int* in_sizes, int n_in,
                              void* d_out, int out_size, void* d_ws, size_t ws_size,
                              hipStream_t stream) {
    const float* feats  = (const float*)d_in[0];
    const float* gamma1 = (const float*)d_in[1];
    const float* beta1  = (const float*)d_in[2];
    const float* W1     = (const float*)d_in[3];
    const float* b1     = (const float*)d_in[4];
    const float* gamma2 = (const float*)d_in[5];
    const float* beta2  = (const float*)d_in[6];
    const float* W2     = (const float*)d_in[7];
    const float* b2     = (const float*)d_in[8];
    const int*   coords = (const int*)d_in[9];
    float* out = (float*)d_out;   // 65536 x 128 fp32 (written only by conv2)

    char* ws = (char*)d_ws;
    unsigned short* h0b  = (unsigned short*)(ws);                    // 2 MB
    unsigned short* h1b  = (unsigned short*)(ws + (2u << 20));       // 16 MB, (o,p) layout
    unsigned short* Wc1f = (unsigned short*)(ws + (18u << 20));      // 2 MB
    unsigned short* Wp2  = (unsigned short*)(ws + (20u << 20));      // 864 KB
    int*   grid32        = (int*)  (ws + (21u << 20));               // 128 KB
    float* stats         = (float*)(ws + (21u << 20) + 131072);      // 512 B
    float* zpage         = (float*)(ws + (21u << 20) + 131072 + 512);// 512 B
    int*   idx_tab       = (int*)  (ws + (22u << 20));               // 7.08 MB
    int*   pidx27        = (int*)  (ws + (30u << 20));               // 864 KB

    // zero stats (128 f) + zpage (128 f) in one async memset
    hipMemsetAsync(stats, 0, 1024, stream);

    k1_kernel<<<288, 256, 0, stream>>>(coords, grid32, feats, stats + 0, stats + 32);
    k2_kernel<<<2104, 256, 0, stream>>>(coords, grid32, idx_tab, pidx27,
                                        W1, W2, Wc1f, Wp2,
                                        feats, stats + 0, stats + 32, gamma1, beta1, h0b);

    // conv1 folded -> bf16 h1b in (o,p) layout + fused GN2 stats
    conv1_fold_kernel<<<8 * (NPAR / 128), 256, 0, stream>>>(h0b, Wc1f, b1, pidx27,
                                                            h1b, zpage,
                                                            stats + 64, stats + 96);

    gn_apply_bf16_kernel<<<512, 256, 0, stream>>>(h1b, stats + 64, stats + 96, gamma2, beta2, NCH);

    // conv2 (27 taps over children) -> fp32 out + residual repeat(feats,8)
    conv2_kernel<<<NCH / 128, 256, 0, stream>>>(h1b, Wp2, b2, idx_tab,
                                                feats, out, zpage);
}

// Round 13
// 207.064 us; speedup vs baseline: 1.6983x; 1.0226x over previous
//
#include <hip/hip_runtime.h>

// Problem constants
#define NPAR   8192      // parents
#define NCH    65536     // children = NPAR*8
#define RES    32
#define EPS    1e-5f

typedef __attribute__((ext_vector_type(8))) short short8;
typedef __attribute__((ext_vector_type(4))) float floatx4;

__device__ __forceinline__ unsigned short f2bf(float f) {
    union { float f; unsigned u; } v; v.f = f;
    unsigned r = v.u + 0x7fffu + ((v.u >> 16) & 1u);   // RNE
    return (unsigned short)(r >> 16);
}
__device__ __forceinline__ float bf2f(unsigned short b) {
    union { unsigned u; float f; } v; v.u = ((unsigned)b) << 16;
    return v.f;
}
// async 16B global->LDS: per-lane global addr, wave-uniform LDS base (+lane*16)
__device__ __forceinline__ void glds16(const void* g, void* l) {
    __builtin_amdgcn_global_load_lds(
        (__attribute__((address_space(1))) const void*)g,
        (__attribute__((address_space(3))) void*)l, 16, 0, 0);
}
// parent-grid tap index for (child-offset o, slot s): e_a = o_a + s_a - 1
__device__ __forceinline__ int k27_of(int o, int s) {
    return (((o >> 2) & 1) + ((s >> 2) & 1)) * 9 +
           (((o >> 1) & 1) + ((s >> 1) & 1)) * 3 +
           ((o & 1) + (s & 1));
}
// fine-tap d-list per axis for (o,s) folding
__device__ __forceinline__ void axis_dlist(int o, int s, int* d, int& n) {
    if (o == 0) { if (s == 0) { d[0] = -1; n = 1; } else { d[0] = 0; d[1] = 1; n = 2; } }
    else        { if (s == 0) { d[0] = -1; d[1] = 0; n = 2; } else { d[0] = 1; n = 1; } }
}

// ---------------------------------------------------------------------------
// K1: blocks [0,32) scatter parents into grid32; blocks [32,288) GN1 stats.
// stats/zpage pre-zeroed by hipMemsetAsync (no intra-kernel ordering hazard).
__global__ void k1_kernel(const int* __restrict__ coords, int* __restrict__ grid32,
                          const float* __restrict__ x, float* __restrict__ sum,
                          float* __restrict__ sq) {
    int b = blockIdx.x;
    int t = threadIdx.x;
    if (b < 32) {
        int p = b * 256 + t;
        grid32[(coords[p*3] << 10) + (coords[p*3+1] << 5) + coords[p*3+2]] = p;
    } else {
        __shared__ float s_sum[32], s_sq[32];
        if (t < 32) { s_sum[t] = 0.0f; s_sq[t] = 0.0f; }
        __syncthreads();
        const float4* x4 = (const float4*)x;
        int total = NPAR * 32;
        int idx0 = (b - 32) * 256 + t;
        int g = idx0 & 31;
        float ls = 0.0f, lq = 0.0f;
        for (int idx = idx0; idx < total; idx += 256 * 256) {
            float4 v = x4[idx];
            ls += v.x + v.y + v.z + v.w;
            lq += v.x * v.x + v.y * v.y + v.z * v.z + v.w * v.w;
        }
        atomicAdd(&s_sum[g], ls);
        atomicAdd(&s_sq[g], lq);
        __syncthreads();
        if (t < 32) { atomicAdd(&sum[t], s_sum[t]); atomicAdd(&sq[t], s_sq[t]); }
    }
}

// ---------------------------------------------------------------------------
// K2, 2104 blocks:
//  [0,256)      child idx_tab[k][R] -> (o,p)-layout row index c*NPAR+r, or -1
//  [256,472)    pack W2 -> Wp2[tap][nb][ks][lane][8] (fragment order)
//  [472,984)    fold W1 per (o,s) + pack -> Wc1f[o*8+s][nb][ks][lane][8]
//  [984,1848)   parent 27-neighbor table pidx27[k][p]
//  [1848,2104)  GN1 apply: feats -> bf16 h0b (reads stats from K1)
__global__ void k2_kernel(const int* __restrict__ coords, const int* __restrict__ grid32,
                          int* __restrict__ idx_tab, int* __restrict__ pidx27,
                          const float* __restrict__ W1, const float* __restrict__ W2,
                          unsigned short* __restrict__ Wc1f, unsigned short* __restrict__ Wp2,
                          const float* __restrict__ x, const float* __restrict__ sum,
                          const float* __restrict__ sq, const float* __restrict__ gamma,
                          const float* __restrict__ beta, unsigned short* __restrict__ y) {
    int b = blockIdx.x;
    if (b < 256) {
        int R = b * 256 + threadIdx.x;   // 65536
        int p = R >> 3, o = R & 7;
        int bx = 2 * coords[p*3]   + ((o >> 2) & 1);
        int by = 2 * coords[p*3+1] + ((o >> 1) & 1);
        int bz = 2 * coords[p*3+2] + (o & 1);
#pragma unroll 1
        for (int k = 0; k < 27; ++k) {
            int fx = bx + k / 9 - 1, fy = by + (k / 3) % 3 - 1, fz = bz + k % 3 - 1;
            int src = -1;
            if ((unsigned)fx < 64u && (unsigned)fy < 64u && (unsigned)fz < 64u) {
                int r = grid32[((fx >> 1) << 10) + ((fy >> 1) << 5) + (fz >> 1)];
                if ((unsigned)r < (unsigned)NPAR)
                    src = (((fx & 1) << 2) + ((fy & 1) << 1) + (fz & 1)) * NPAR + r;
            }
            idx_tab[k * NCH + R] = src;
        }
    } else if (b < 472) {
        int rem = (b - 256) * 256 + threadIdx.x;   // < 55296
        int lane = rem & 63;
        int ks   = (rem >> 6) & 3;
        int nb   = (rem >> 8) & 7;
        int tap  = rem >> 11;                       // 0..26
        int n  = nb * 16 + (lane & 15);
        int k0 = ks * 32 + (lane >> 4) * 8;
        unsigned short v[8];
#pragma unroll
        for (int j = 0; j < 8; ++j) v[j] = f2bf(W2[tap * 16384 + (k0 + j) * 128 + n]);
        uint4 pk;
        pk.x = (unsigned)v[0] | ((unsigned)v[1] << 16);
        pk.y = (unsigned)v[2] | ((unsigned)v[3] << 16);
        pk.z = (unsigned)v[4] | ((unsigned)v[5] << 16);
        pk.w = (unsigned)v[6] | ((unsigned)v[7] << 16);
        *(uint4*)&Wp2[(long)rem * 8] = pk;
    } else if (b < 984) {
        int rem = (b - 472) * 256 + threadIdx.x;   // < 131072
        int lane  = rem & 63;
        int ks    = (rem >> 6) & 3;
        int nb    = (rem >> 8) & 7;
        int combo = rem >> 11;                      // 0..63 = o*8+s
        int o = combo >> 3, s = combo & 7;
        int n  = nb * 16 + (lane & 15);
        int k0 = ks * 32 + (lane >> 4) * 8;
        int d0[2], d1[2], d2[2], n0, n1, n2;
        axis_dlist((o >> 2) & 1, (s >> 2) & 1, d0, n0);
        axis_dlist((o >> 1) & 1, (s >> 1) & 1, d1, n1);
        axis_dlist(o & 1,        s & 1,        d2, n2);
        unsigned short v[8];
#pragma unroll
        for (int j = 0; j < 8; ++j) {
            float acc = 0.0f;
            for (int a = 0; a < n0; ++a)
                for (int bb = 0; bb < n1; ++bb)
                    for (int cc = 0; cc < n2; ++cc) {
                        int kk = (d0[a] + 1) * 9 + (d1[bb] + 1) * 3 + (d2[cc] + 1);
                        acc += W1[kk * 16384 + (k0 + j) * 128 + n];
                    }
            v[j] = f2bf(acc);
        }
        uint4 pk;
        pk.x = (unsigned)v[0] | ((unsigned)v[1] << 16);
        pk.y = (unsigned)v[2] | ((unsigned)v[3] << 16);
        pk.z = (unsigned)v[4] | ((unsigned)v[5] << 16);
        pk.w = (unsigned)v[6] | ((unsigned)v[7] << 16);
        *(uint4*)&Wc1f[(long)rem * 8] = pk;
    } else if (b < 1848) {
        int gid = (b - 984) * 256 + threadIdx.x;   // < 221184 = 27*8192
        int k = gid >> 13, p = gid & 8191;
        int nx = coords[p*3]   + k / 9 - 1;
        int ny = coords[p*3+1] + (k / 3) % 3 - 1;
        int nz = coords[p*3+2] + k % 3 - 1;
        int src = -1;
        if ((unsigned)nx < 32u && (unsigned)ny < 32u && (unsigned)nz < 32u) {
            int r = grid32[(nx << 10) + (ny << 5) + nz];
            if ((unsigned)r < (unsigned)NPAR) src = r;
        }
        pidx27[k * NPAR + p] = src;
    } else {
        const float4* x4 = (const float4*)x;
        uint2* y2 = (uint2*)y;
        const float4* g4 = (const float4*)gamma;
        const float4* b4 = (const float4*)beta;
        float cnt = (float)NPAR * 4.0f;
        int total = NPAR * 32;
        for (int idx = (b - 1848) * 256 + threadIdx.x; idx < total; idx += 256 * 256) {
            int c4 = idx & 31;
            float mean = sum[c4] / cnt;
            float var = sq[c4] / cnt - mean * mean;
            float rstd = rsqrtf(var + EPS);
            float4 v = x4[idx];
            float4 gm = g4[c4];
            float4 bt = b4[c4];
            float a[4] = {v.x, v.y, v.z, v.w};
            float gg[4] = {gm.x, gm.y, gm.z, gm.w};
            float bb[4] = {bt.x, bt.y, bt.z, bt.w};
            unsigned short o[4];
#pragma unroll
            for (int i = 0; i < 4; ++i) {
                float tv = (a[i] - mean) * rstd * gg[i] + bb[i];
                o[i] = f2bf(tv / (1.0f + __expf(-tv)));
            }
            uint2 pk;
            pk.x = (unsigned)o[0] | ((unsigned)o[1] << 16);
            pk.y = (unsigned)o[2] | ((unsigned)o[3] << 16);
            y2[idx] = pk;
        }
    }
}

// ---------------------------------------------------------------------------
// bf16 in -> bf16 out, in place (GN2); layout-agnostic elementwise
__global__ void gn_apply_bf16_kernel(unsigned short* __restrict__ x,
                                     const float* __restrict__ sum, const float* __restrict__ sq,
                                     const float* __restrict__ gamma, const float* __restrict__ beta,
                                     int nrows) {
    uint2* x2 = (uint2*)x;
    const float4* g4 = (const float4*)gamma;
    const float4* b4 = (const float4*)beta;
    float cnt = (float)nrows * 4.0f;
    int total = nrows * 32;
    for (int idx = blockIdx.x * blockDim.x + threadIdx.x; idx < total;
         idx += gridDim.x * blockDim.x) {
        int c4 = idx & 31;
        float mean = sum[c4] / cnt;
        float var = sq[c4] / cnt - mean * mean;
        float rstd = rsqrtf(var + EPS);
        uint2 pk = x2[idx];
        float a[4] = {bf2f((unsigned short)(pk.x & 0xffff)), bf2f((unsigned short)(pk.x >> 16)),
                      bf2f((unsigned short)(pk.y & 0xffff)), bf2f((unsigned short)(pk.y >> 16))};
        float4 gm = g4[c4];
        float4 bt = b4[c4];
        float gg[4] = {gm.x, gm.y, gm.z, gm.w};
        float bb[4] = {bt.x, bt.y, bt.z, bt.w};
        unsigned short o[4];
#pragma unroll
        for (int i = 0; i < 4; ++i) {
            float tv = (a[i] - mean) * rstd * gg[i] + bb[i];
            o[i] = f2bf(tv / (1.0f + __expf(-tv)));
        }
        pk.x = (unsigned)o[0] | ((unsigned)o[1] << 16);
        pk.y = (unsigned)o[2] | ((unsigned)o[3] << 16);
        x2[idx] = pk;
    }
}

// ---------------------------------------------------------------------------
// CONV1 FOLDED: block = (o, 128 parents), 256 threads = 4 waves (2x2).
// B REGISTER DOUBLE-BUFFER: slot s+1's B-frags loaded into VGPRs during slot
// s's MFMA phase -> after the barrier MFMAs start with B in regs, A in LDS
// (no load latency inside the compute phase). launch_bounds(256,2): LDS caps
// occupancy at 2 blocks/CU anyway, so the +128 VGPRs are free.
__global__ void __launch_bounds__(256, 2) conv1_fold_kernel(
    const unsigned short* __restrict__ Ag, const unsigned short* __restrict__ Wc1f,
    const float* __restrict__ bias, const int* __restrict__ pidx27,
    unsigned short* __restrict__ outp, const float* __restrict__ zpage,
    float* __restrict__ gsum, float* __restrict__ gsq) {
    __shared__ unsigned short A_lds[2][16384];   // 2 x 32 KB

    int t = threadIdx.x;
    int o  = blockIdx.x & 7;
    int P0 = (blockIdx.x >> 3) << 7;            // 128 parents per block
    const unsigned short* Wb = Wc1f + ((long)o << 17);   // o*8*16384
    int wv = t >> 6, lane = t & 63, quad = lane >> 4, l16 = lane & 15;
    int wm = wv & 1, wn = wv >> 1;
    int r16 = lane >> 2, cch = lane & 3;
    int c0 = wv * 2, c1 = wv * 2 + 1;
    int row0 = ((c0 >> 2) << 6) + ((c0 & 3) << 4) + r16;
    int row1 = ((c1 >> 2) << 6) + ((c1 & 3) << 4) + r16;
    int base0 = ((c0 >> 2) << 13) + ((c0 & 3) << 11);
    int base1 = ((c1 >> 2) << 13) + ((c1 & 3) << 11);
    const unsigned short* zsrc = (const unsigned short*)zpage;

    floatx4 acc[4][4];
#pragma unroll
    for (int mt = 0; mt < 4; ++mt)
#pragma unroll
        for (int nt = 0; nt < 4; ++nt)
            acc[mt][nt] = (floatx4){0.f, 0.f, 0.f, 0.f};

    // ---- prolog: slot 0 A into buf 0, slot 0 B into regs
    int iv0 = pidx27[k27_of(o, 0) * NPAR + P0 + row0];
    int iv1 = pidx27[k27_of(o, 0) * NPAR + P0 + row1];
    {
        const unsigned short* g0 = (iv0 >= 0) ? Ag + (long)iv0 * 128 : zsrc;
        const unsigned short* g1 = (iv1 >= 0) ? Ag + (long)iv1 * 128 : zsrc;
#pragma unroll
        for (int i = 0; i < 4; ++i) glds16(g0 + i * 32 + cch * 8, &A_lds[0][base0 + i * 512]);
#pragma unroll
        for (int i = 0; i < 4; ++i) glds16(g1 + i * 32 + cch * 8, &A_lds[0][base1 + i * 512]);
    }
    short8 bcur[4][4], bnxt[4][4];
#pragma unroll
    for (int nt = 0; nt < 4; ++nt)
#pragma unroll
        for (int ks = 0; ks < 4; ++ks)
            bcur[nt][ks] = *(const short8*)&Wb[((((0 << 3) + (wn * 4 + nt)) << 2) + ks) * 512 + (lane << 3)];
    int nv0 = pidx27[k27_of(o, 1) * NPAR + P0 + row0];
    int nv1 = pidx27[k27_of(o, 1) * NPAR + P0 + row1];
    __syncthreads();

#pragma unroll 1
    for (int s = 0; s < 8; ++s) {
        int cur = s & 1;
        if (s < 7) {
            const unsigned short* g0 = (nv0 >= 0) ? Ag + (long)nv0 * 128 : zsrc;
            const unsigned short* g1 = (nv1 >= 0) ? Ag + (long)nv1 * 128 : zsrc;
#pragma unroll
            for (int i = 0; i < 4; ++i) glds16(g0 + i * 32 + cch * 8, &A_lds[1 - cur][base0 + i * 512]);
#pragma unroll
            for (int i = 0; i < 4; ++i) glds16(g1 + i * 32 + cch * 8, &A_lds[1 - cur][base1 + i * 512]);
            // B for slot s+1 -> regs (landed by the barrier's vmcnt drain)
#pragma unroll
            for (int nt = 0; nt < 4; ++nt)
#pragma unroll
                for (int ks = 0; ks < 4; ++ks)
                    bnxt[nt][ks] = *(const short8*)&Wb[(((((s + 1) << 3) + (wn * 4 + nt)) << 2) + ks) * 512 + (lane << 3)];
            if (s < 6) {
                nv0 = pidx27[k27_of(o, s + 2) * NPAR + P0 + row0];
                nv1 = pidx27[k27_of(o, s + 2) * NPAR + P0 + row1];
            }
        }
#pragma unroll
        for (int ks = 0; ks < 4; ++ks) {
            short8 afr[4];
#pragma unroll
            for (int mt = 0; mt < 4; ++mt)
                afr[mt] = *(const short8*)&A_lds[cur][(wm << 13) + (mt << 11) + (ks << 9) + (l16 << 5) + (quad << 3)];
#pragma unroll
            for (int mt = 0; mt < 4; ++mt)
#pragma unroll
                for (int nt = 0; nt < 4; ++nt)
                    acc[mt][nt] = __builtin_amdgcn_mfma_f32_16x16x32_bf16(
                        afr[mt], bcur[nt][ks], acc[mt][nt], 0, 0, 0);
        }
        __syncthreads();
        if (s < 7) {
#pragma unroll
            for (int nt = 0; nt < 4; ++nt)
#pragma unroll
                for (int ks = 0; ks < 4; ++ks)
                    bcur[nt][ks] = bnxt[nt][ks];
        }
    }

    // ---- epilogue: coalesced bf16 store at row o*NPAR + p, fused GN2 stats
    float s_[4] = {0.f, 0.f, 0.f, 0.f}, q_[4] = {0.f, 0.f, 0.f, 0.f};
#pragma unroll
    for (int nt = 0; nt < 4; ++nt) {
        int col = wn * 64 + nt * 16 + l16;
        float bv = bias[col];
#pragma unroll
        for (int mt = 0; mt < 4; ++mt) {
#pragma unroll
            for (int r = 0; r < 4; ++r) {
                int prow = wm * 64 + mt * 16 + quad * 4 + r;
                long R = (long)o * NPAR + P0 + prow;
                float v = acc[mt][nt][r] + bv;
                unsigned short u = f2bf(v);
                outp[R * 128 + col] = u;
                float vr = bf2f(u);
                s_[nt] += vr;
                q_[nt] += vr * vr;
            }
        }
    }
    float* sred = (float*)A_lds;   // safe: loop's trailing barrier passed
    if (t < 64) sred[t] = 0.0f;
    __syncthreads();
#pragma unroll
    for (int nt = 0; nt < 4; ++nt) {
        int g = (wn * 64 + nt * 16 + l16) >> 2;
        atomicAdd(&sred[g], s_[nt]);
        atomicAdd(&sred[32 + g], q_[nt]);
    }
    __syncthreads();
    if (t < 32) { atomicAdd(&gsum[t], sred[t]); atomicAdd(&gsq[t], sred[32 + t]); }
}

// ---------------------------------------------------------------------------
// CONV2 with B register double-buffer (same pipeline decoupling as conv1).
__global__ void __launch_bounds__(256, 2) conv2_kernel(
    const unsigned short* __restrict__ Ag, const unsigned short* __restrict__ Wp,
    const float* __restrict__ bias, const int* __restrict__ idx_tab,
    const float* __restrict__ resid, float* __restrict__ outp,
    const float* __restrict__ zpage) {
    __shared__ unsigned short A_lds[2][16384];   // 2 x 32 KB

    int t = threadIdx.x;
    int R0 = blockIdx.x * 128;
    int wv = t >> 6, lane = t & 63, quad = lane >> 4, l16 = lane & 15;
    int wm = wv & 1, wn = wv >> 1;
    int r16 = lane >> 2, cch = lane & 3;
    int c0 = wv * 2, c1 = wv * 2 + 1;
    int row0 = ((c0 >> 2) << 6) + ((c0 & 3) << 4) + r16;
    int row1 = ((c1 >> 2) << 6) + ((c1 & 3) << 4) + r16;
    int base0 = ((c0 >> 2) << 13) + ((c0 & 3) << 11);
    int base1 = ((c1 >> 2) << 13) + ((c1 & 3) << 11);
    const unsigned short* zsrc = (const unsigned short*)zpage;

    floatx4 acc[4][4];
#pragma unroll
    for (int mt = 0; mt < 4; ++mt)
#pragma unroll
        for (int nt = 0; nt < 4; ++nt)
            acc[mt][nt] = (floatx4){0.f, 0.f, 0.f, 0.f};

    int iv0 = idx_tab[R0 + row0], iv1 = idx_tab[R0 + row1];
    {
        const unsigned short* g0 = (iv0 >= 0) ? Ag + (long)iv0 * 128 : zsrc;
        const unsigned short* g1 = (iv1 >= 0) ? Ag + (long)iv1 * 128 : zsrc;
#pragma unroll
        for (int i = 0; i < 4; ++i) glds16(g0 + i * 32 + cch * 8, &A_lds[0][base0 + i * 512]);
#pragma unroll
        for (int i = 0; i < 4; ++i) glds16(g1 + i * 32 + cch * 8, &A_lds[0][base1 + i * 512]);
    }
    short8 bcur[4][4], bnxt[4][4];
#pragma unroll
    for (int nt = 0; nt < 4; ++nt)
#pragma unroll
        for (int ks = 0; ks < 4; ++ks)
            bcur[nt][ks] = *(const short8*)&Wp[((((0 << 3) + (wn * 4 + nt)) << 2) + ks) * 512 + (lane << 3)];
    int nv0 = idx_tab[NCH + R0 + row0], nv1 = idx_tab[NCH + R0 + row1];
    __syncthreads();

#pragma unroll 1
    for (int k = 0; k < 27; ++k) {
        int cur = k & 1;
        if (k < 26) {
            const unsigned short* g0 = (nv0 >= 0) ? Ag + (long)nv0 * 128 : zsrc;
            const unsigned short* g1 = (nv1 >= 0) ? Ag + (long)nv1 * 128 : zsrc;
#pragma unroll
            for (int i = 0; i < 4; ++i) glds16(g0 + i * 32 + cch * 8, &A_lds[1 - cur][base0 + i * 512]);
#pragma unroll
            for (int i = 0; i < 4; ++i) glds16(g1 + i * 32 + cch * 8, &A_lds[1 - cur][base1 + i * 512]);
            // B for tap k+1 -> regs (landed by the barrier's vmcnt drain)
#pragma unroll
            for (int nt = 0; nt < 4; ++nt)
#pragma unroll
                for (int ks = 0; ks < 4; ++ks)
                    bnxt[nt][ks] = *(const short8*)&Wp[(((((k + 1) << 3) + (wn * 4 + nt)) << 2) + ks) * 512 + (lane << 3)];
            if (k < 25) {
                nv0 = idx_tab[(k + 2) * NCH + R0 + row0];
                nv1 = idx_tab[(k + 2) * NCH + R0 + row1];
            }
        }
#pragma unroll
        for (int ks = 0; ks < 4; ++ks) {
            short8 afr[4];
#pragma unroll
            for (int mt = 0; mt < 4; ++mt)
                afr[mt] = *(const short8*)&A_lds[cur][(wm << 13) + (mt << 11) + (ks << 9) + (l16 << 5) + (quad << 3)];
#pragma unroll
            for (int mt = 0; mt < 4; ++mt)
#pragma unroll
                for (int nt = 0; nt < 4; ++nt)
                    acc[mt][nt] = __builtin_amdgcn_mfma_f32_16x16x32_bf16(
                        afr[mt], bcur[nt][ks], acc[mt][nt], 0, 0, 0);
        }
        __syncthreads();
        if (k < 26) {
#pragma unroll
            for (int nt = 0; nt < 4; ++nt)
#pragma unroll
                for (int ks = 0; ks < 4; ++ks)
                    bcur[nt][ks] = bnxt[nt][ks];
        }
    }

#pragma unroll
    for (int nt = 0; nt < 4; ++nt) {
        int col = wn * 64 + nt * 16 + l16;
        float bv = bias[col];
#pragma unroll
        for (int mt = 0; mt < 4; ++mt) {
#pragma unroll
            for (int r = 0; r < 4; ++r) {
                int row = wm * 64 + mt * 16 + quad * 4 + r;
                long R = (long)R0 + row;
                float v = acc[mt][nt][r] + bv + resid[(R >> 3) * 128 + col];
                outp[R * 128 + col] = v;
            }
        }
    }
}

// ---------------------------------------------------------------------------
extern "C" void kernel_launch(void* const* d_in, const int* in_sizes, int n_in,
                              void* d_out, int out_size, void* d_ws, size_t ws_size,
                              hipStream_t stream) {
    const float* feats  = (const float*)d_in[0];
    const float* gamma1 = (const float*)d_in[1];
    const float* beta1  = (const float*)d_in[2];
    const float* W1     = (const float*)d_in[3];
    const float* b1     = (const float*)d_in[4];
    const float* gamma2 = (const float*)d_in[5];
    const float* beta2  = (const float*)d_in[6];
    const float* W2     = (const float*)d_in[7];
    const float* b2     = (const float*)d_in[8];
    const int*   coords = (const int*)d_in[9];
    float* out = (float*)d_out;   // 65536 x 128 fp32 (written only by conv2)

    char* ws = (char*)d_ws;
    unsigned short* h0b  = (unsigned short*)(ws);                    // 2 MB
    unsigned short* h1b  = (unsigned short*)(ws + (2u << 20));       // 16 MB, (o,p) layout
    unsigned short* Wc1f = (unsigned short*)(ws + (18u << 20));      // 2 MB
    unsigned short* Wp2  = (unsigned short*)(ws + (20u << 20));      // 864 KB
    int*   grid32        = (int*)  (ws + (21u << 20));               // 128 KB
    float* stats         = (float*)(ws + (21u << 20) + 131072);      // 512 B
    float* zpage         = (float*)(ws + (21u << 20) + 131072 + 512);// 512 B
    int*   idx_tab       = (int*)  (ws + (22u << 20));               // 7.08 MB
    int*   pidx27        = (int*)  (ws + (30u << 20));               // 864 KB

    // zero stats (128 f) + zpage (128 f) in one async memset
    hipMemsetAsync(stats, 0, 1024, stream);

    k1_kernel<<<288, 256, 0, stream>>>(coords, grid32, feats, stats + 0, stats + 32);
    k2_kernel<<<2104, 256, 0, stream>>>(coords, grid32, idx_tab, pidx27,
                                        W1, W2, Wc1f, Wp2,
                                        feats, stats + 0, stats + 32, gamma1, beta1, h0b);

    // conv1 folded -> bf16 h1b in (o,p) layout + fused GN2 stats
    conv1_fold_kernel<<<8 * (NPAR / 128), 256, 0, stream>>>(h0b, Wc1f, b1, pidx27,
                                                            h1b, zpage,
                                                            stats + 64, stats + 96);

    gn_apply_bf16_kernel<<<512, 256, 0, stream>>>(h1b, stats + 64, stats + 96, gamma2, beta2, NCH);

    // conv2 (27 taps over children) -> fp32 out + residual repeat(feats,8)
    conv2_kernel<<<NCH / 128, 256, 0, stream>>>(h1b, Wp2, b2, idx_tab,
                                                feats, out, zpage);
}

// Round 14
// 205.657 us; speedup vs baseline: 1.7099x; 1.0068x over previous
//
#include <hip/hip_runtime.h>

// Problem constants
#define NPAR   8192      // parents
#define NCH    65536     // children = NPAR*8
#define RES    32
#define EPS    1e-5f

typedef __attribute__((ext_vector_type(8))) short short8;
typedef __attribute__((ext_vector_type(4))) float floatx4;

__device__ __forceinline__ unsigned short f2bf(float f) {
    union { float f; unsigned u; } v; v.f = f;
    unsigned r = v.u + 0x7fffu + ((v.u >> 16) & 1u);   // RNE
    return (unsigned short)(r >> 16);
}
__device__ __forceinline__ float bf2f(unsigned short b) {
    union { unsigned u; float f; } v; v.u = ((unsigned)b) << 16;
    return v.f;
}
// async 16B global->LDS: per-lane global addr, wave-uniform LDS base (+lane*16)
__device__ __forceinline__ void glds16(const void* g, void* l) {
    __builtin_amdgcn_global_load_lds(
        (__attribute__((address_space(1))) const void*)g,
        (__attribute__((address_space(3))) void*)l, 16, 0, 0);
}
// parent-grid tap index for (child-offset o, slot s): e_a = o_a + s_a - 1
__device__ __forceinline__ int k27_of(int o, int s) {
    return (((o >> 2) & 1) + ((s >> 2) & 1)) * 9 +
           (((o >> 1) & 1) + ((s >> 1) & 1)) * 3 +
           ((o & 1) + (s & 1));
}
// fine-tap d-list per axis for (o,s) folding
__device__ __forceinline__ void axis_dlist(int o, int s, int* d, int& n) {
    if (o == 0) { if (s == 0) { d[0] = -1; n = 1; } else { d[0] = 0; d[1] = 1; n = 2; } }
    else        { if (s == 0) { d[0] = -1; d[1] = 0; n = 2; } else { d[0] = 1; n = 1; } }
}

// ---------------------------------------------------------------------------
// K1: blocks [0,32) scatter parents into grid32; blocks [32,288) GN1 stats.
__global__ void k1_kernel(const int* __restrict__ coords, int* __restrict__ grid32,
                          const float* __restrict__ x, float* __restrict__ sum,
                          float* __restrict__ sq) {
    int b = blockIdx.x;
    int t = threadIdx.x;
    if (b < 32) {
        int p = b * 256 + t;
        grid32[(coords[p*3] << 10) + (coords[p*3+1] << 5) + coords[p*3+2]] = p;
    } else {
        __shared__ float s_sum[32], s_sq[32];
        if (t < 32) { s_sum[t] = 0.0f; s_sq[t] = 0.0f; }
        __syncthreads();
        const float4* x4 = (const float4*)x;
        int total = NPAR * 32;
        int idx0 = (b - 32) * 256 + t;
        int g = idx0 & 31;
        float ls = 0.0f, lq = 0.0f;
        for (int idx = idx0; idx < total; idx += 256 * 256) {
            float4 v = x4[idx];
            ls += v.x + v.y + v.z + v.w;
            lq += v.x * v.x + v.y * v.y + v.z * v.z + v.w * v.w;
        }
        atomicAdd(&s_sum[g], ls);
        atomicAdd(&s_sq[g], lq);
        __syncthreads();
        if (t < 32) { atomicAdd(&sum[t], s_sum[t]); atomicAdd(&sq[t], s_sq[t]); }
    }
}

// ---------------------------------------------------------------------------
// K2, 2104 blocks: idx_tab / W2 pack / W1 fold+pack / pidx27 / GN1 apply
__global__ void k2_kernel(const int* __restrict__ coords, const int* __restrict__ grid32,
                          int* __restrict__ idx_tab, int* __restrict__ pidx27,
                          const float* __restrict__ W1, const float* __restrict__ W2,
                          unsigned short* __restrict__ Wc1f, unsigned short* __restrict__ Wp2,
                          const float* __restrict__ x, const float* __restrict__ sum,
                          const float* __restrict__ sq, const float* __restrict__ gamma,
                          const float* __restrict__ beta, unsigned short* __restrict__ y) {
    int b = blockIdx.x;
    if (b < 256) {
        int R = b * 256 + threadIdx.x;   // 65536
        int p = R >> 3, o = R & 7;
        int bx = 2 * coords[p*3]   + ((o >> 2) & 1);
        int by = 2 * coords[p*3+1] + ((o >> 1) & 1);
        int bz = 2 * coords[p*3+2] + (o & 1);
#pragma unroll 1
        for (int k = 0; k < 27; ++k) {
            int fx = bx + k / 9 - 1, fy = by + (k / 3) % 3 - 1, fz = bz + k % 3 - 1;
            int src = -1;
            if ((unsigned)fx < 64u && (unsigned)fy < 64u && (unsigned)fz < 64u) {
                int r = grid32[((fx >> 1) << 10) + ((fy >> 1) << 5) + (fz >> 1)];
                if ((unsigned)r < (unsigned)NPAR)
                    src = (((fx & 1) << 2) + ((fy & 1) << 1) + (fz & 1)) * NPAR + r;
            }
            idx_tab[k * NCH + R] = src;
        }
    } else if (b < 472) {
        int rem = (b - 256) * 256 + threadIdx.x;   // < 55296
        int lane = rem & 63;
        int ks   = (rem >> 6) & 3;
        int nb   = (rem >> 8) & 7;
        int tap  = rem >> 11;                       // 0..26
        int n  = nb * 16 + (lane & 15);
        int k0 = ks * 32 + (lane >> 4) * 8;
        unsigned short v[8];
#pragma unroll
        for (int j = 0; j < 8; ++j) v[j] = f2bf(W2[tap * 16384 + (k0 + j) * 128 + n]);
        uint4 pk;
        pk.x = (unsigned)v[0] | ((unsigned)v[1] << 16);
        pk.y = (unsigned)v[2] | ((unsigned)v[3] << 16);
        pk.z = (unsigned)v[4] | ((unsigned)v[5] << 16);
        pk.w = (unsigned)v[6] | ((unsigned)v[7] << 16);
        *(uint4*)&Wp2[(long)rem * 8] = pk;
    } else if (b < 984) {
        int rem = (b - 472) * 256 + threadIdx.x;   // < 131072
        int lane  = rem & 63;
        int ks    = (rem >> 6) & 3;
        int nb    = (rem >> 8) & 7;
        int combo = rem >> 11;                      // 0..63 = o*8+s
        int o = combo >> 3, s = combo & 7;
        int n  = nb * 16 + (lane & 15);
        int k0 = ks * 32 + (lane >> 4) * 8;
        int d0[2], d1[2], d2[2], n0, n1, n2;
        axis_dlist((o >> 2) & 1, (s >> 2) & 1, d0, n0);
        axis_dlist((o >> 1) & 1, (s >> 1) & 1, d1, n1);
        axis_dlist(o & 1,        s & 1,        d2, n2);
        unsigned short v[8];
#pragma unroll
        for (int j = 0; j < 8; ++j) {
            float acc = 0.0f;
            for (int a = 0; a < n0; ++a)
                for (int bb = 0; bb < n1; ++bb)
                    for (int cc = 0; cc < n2; ++cc) {
                        int kk = (d0[a] + 1) * 9 + (d1[bb] + 1) * 3 + (d2[cc] + 1);
                        acc += W1[kk * 16384 + (k0 + j) * 128 + n];
                    }
            v[j] = f2bf(acc);
        }
        uint4 pk;
        pk.x = (unsigned)v[0] | ((unsigned)v[1] << 16);
        pk.y = (unsigned)v[2] | ((unsigned)v[3] << 16);
        pk.z = (unsigned)v[4] | ((unsigned)v[5] << 16);
        pk.w = (unsigned)v[6] | ((unsigned)v[7] << 16);
        *(uint4*)&Wc1f[(long)rem * 8] = pk;
    } else if (b < 1848) {
        int gid = (b - 984) * 256 + threadIdx.x;   // < 221184 = 27*8192
        int k = gid >> 13, p = gid & 8191;
        int nx = coords[p*3]   + k / 9 - 1;
        int ny = coords[p*3+1] + (k / 3) % 3 - 1;
        int nz = coords[p*3+2] + k % 3 - 1;
        int src = -1;
        if ((unsigned)nx < 32u && (unsigned)ny < 32u && (unsigned)nz < 32u) {
            int r = grid32[(nx << 10) + (ny << 5) + nz];
            if ((unsigned)r < (unsigned)NPAR) src = r;
        }
        pidx27[k * NPAR + p] = src;
    } else {
        const float4* x4 = (const float4*)x;
        uint2* y2 = (uint2*)y;
        const float4* g4 = (const float4*)gamma;
        const float4* b4 = (const float4*)beta;
        float cnt = (float)NPAR * 4.0f;
        int total = NPAR * 32;
        for (int idx = (b - 1848) * 256 + threadIdx.x; idx < total; idx += 256 * 256) {
            int c4 = idx & 31;
            float mean = sum[c4] / cnt;
            float var = sq[c4] / cnt - mean * mean;
            float rstd = rsqrtf(var + EPS);
            float4 v = x4[idx];
            float4 gm = g4[c4];
            float4 bt = b4[c4];
            float a[4] = {v.x, v.y, v.z, v.w};
            float gg[4] = {gm.x, gm.y, gm.z, gm.w};
            float bb[4] = {bt.x, bt.y, bt.z, bt.w};
            unsigned short o[4];
#pragma unroll
            for (int i = 0; i < 4; ++i) {
                float tv = (a[i] - mean) * rstd * gg[i] + bb[i];
                o[i] = f2bf(tv / (1.0f + __expf(-tv)));
            }
            uint2 pk;
            pk.x = (unsigned)o[0] | ((unsigned)o[1] << 16);
            pk.y = (unsigned)o[2] | ((unsigned)o[3] << 16);
            y2[idx] = pk;
        }
    }
}

// ---------------------------------------------------------------------------
// bf16 in -> bf16 out, in place (GN2); layout-agnostic elementwise
__global__ void gn_apply_bf16_kernel(unsigned short* __restrict__ x,
                                     const float* __restrict__ sum, const float* __restrict__ sq,
                                     const float* __restrict__ gamma, const float* __restrict__ beta,
                                     int nrows) {
    uint2* x2 = (uint2*)x;
    const float4* g4 = (const float4*)gamma;
    const float4* b4 = (const float4*)beta;
    float cnt = (float)nrows * 4.0f;
    int total = nrows * 32;
    for (int idx = blockIdx.x * blockDim.x + threadIdx.x; idx < total;
         idx += gridDim.x * blockDim.x) {
        int c4 = idx & 31;
        float mean = sum[c4] / cnt;
        float var = sq[c4] / cnt - mean * mean;
        float rstd = rsqrtf(var + EPS);
        uint2 pk = x2[idx];
        float a[4] = {bf2f((unsigned short)(pk.x & 0xffff)), bf2f((unsigned short)(pk.x >> 16)),
                      bf2f((unsigned short)(pk.y & 0xffff)), bf2f((unsigned short)(pk.y >> 16))};
        float4 gm = g4[c4];
        float4 bt = b4[c4];
        float gg[4] = {gm.x, gm.y, gm.z, gm.w};
        float bb[4] = {bt.x, bt.y, bt.z, bt.w};
        unsigned short o[4];
#pragma unroll
        for (int i = 0; i < 4; ++i) {
            float tv = (a[i] - mean) * rstd * gg[i] + bb[i];
            o[i] = f2bf(tv / (1.0f + __expf(-tv)));
        }
        pk.x = (unsigned)o[0] | ((unsigned)o[1] << 16);
        pk.y = (unsigned)o[2] | ((unsigned)o[3] << 16);
        x2[idx] = pk;
    }
}

// ---------------------------------------------------------------------------
// Shared MFMA helpers (macro-free inline fns over fixed-shape arrays)
__device__ __forceinline__ void mfma_phase(
    const unsigned short* __restrict__ Abuf, short8 (&bfr)[4][4],
    floatx4 (&acc)[4][4], int wm, int l16, int quad) {
#pragma unroll
    for (int ks = 0; ks < 4; ++ks) {
        short8 afr[4];
#pragma unroll
        for (int mt = 0; mt < 4; ++mt)
            afr[mt] = *(const short8*)&Abuf[(wm << 13) + (mt << 11) + (ks << 9) + (l16 << 5) + (quad << 3)];
#pragma unroll
        for (int mt = 0; mt < 4; ++mt)
#pragma unroll
            for (int nt = 0; nt < 4; ++nt)
                acc[mt][nt] = __builtin_amdgcn_mfma_f32_16x16x32_bf16(
                    afr[mt], bfr[nt][ks], acc[mt][nt], 0, 0, 0);
    }
}
__device__ __forceinline__ void loadB(const unsigned short* __restrict__ Wtap,
                                      short8 (&bfr)[4][4], int wn, int lane) {
#pragma unroll
    for (int nt = 0; nt < 4; ++nt)
#pragma unroll
        for (int ks = 0; ks < 4; ++ks)
            bfr[nt][ks] = *(const short8*)&Wtap[(((wn * 4 + nt) << 2) + ks) * 512 + (lane << 3)];
}
__device__ __forceinline__ void stageA(const unsigned short* __restrict__ Ag,
                                       int iv0, int iv1, const unsigned short* zsrc,
                                       unsigned short* __restrict__ buf,
                                       int base0, int base1, int cch) {
    const unsigned short* g0 = (iv0 >= 0) ? Ag + (long)iv0 * 128 : zsrc;
    const unsigned short* g1 = (iv1 >= 0) ? Ag + (long)iv1 * 128 : zsrc;
#pragma unroll
    for (int i = 0; i < 4; ++i) glds16(g0 + i * 32 + cch * 8, &buf[base0 + i * 512]);
#pragma unroll
    for (int i = 0; i < 4; ++i) glds16(g1 + i * 32 + cch * 8, &buf[base1 + i * 512]);
}

// ---------------------------------------------------------------------------
// CONV1 FOLDED — 2x-unrolled slot loop, ping-pong B register sets (bA/bB, no
// copies) so the compiler must keep the prefetched B set live across the
// barrier (r13's single-set + copy collapsed to VGPR=116 = partial pipeline).
__global__ void __launch_bounds__(256, 2) conv1_fold_kernel(
    const unsigned short* __restrict__ Ag, const unsigned short* __restrict__ Wc1f,
    const float* __restrict__ bias, const int* __restrict__ pidx27,
    unsigned short* __restrict__ outp, const float* __restrict__ zpage,
    float* __restrict__ gsum, float* __restrict__ gsq) {
    __shared__ unsigned short A_lds[2][16384];   // 2 x 32 KB

    int t = threadIdx.x;
    int o  = blockIdx.x & 7;
    int P0 = (blockIdx.x >> 3) << 7;            // 128 parents per block
    const unsigned short* Wb = Wc1f + ((long)o << 17);
    int wv = t >> 6, lane = t & 63, quad = lane >> 4, l16 = lane & 15;
    int wm = wv & 1, wn = wv >> 1;
    int r16 = lane >> 2, cch = lane & 3;
    int c0 = wv * 2, c1 = wv * 2 + 1;
    int row0 = ((c0 >> 2) << 6) + ((c0 & 3) << 4) + r16;
    int row1 = ((c1 >> 2) << 6) + ((c1 & 3) << 4) + r16;
    int base0 = ((c0 >> 2) << 13) + ((c0 & 3) << 11);
    int base1 = ((c1 >> 2) << 13) + ((c1 & 3) << 11);
    const unsigned short* zsrc = (const unsigned short*)zpage;

    floatx4 acc[4][4];
#pragma unroll
    for (int mt = 0; mt < 4; ++mt)
#pragma unroll
        for (int nt = 0; nt < 4; ++nt)
            acc[mt][nt] = (floatx4){0.f, 0.f, 0.f, 0.f};
    short8 bA[4][4], bB[4][4];

    // ---- prolog: slot 0 A -> buf0, slot 0 B -> bA
    stageA(Ag, pidx27[k27_of(o, 0) * NPAR + P0 + row0],
               pidx27[k27_of(o, 0) * NPAR + P0 + row1], zsrc, A_lds[0], base0, base1, cch);
    loadB(Wb, bA, wn, lane);
    int nv0 = pidx27[k27_of(o, 1) * NPAR + P0 + row0];
    int nv1 = pidx27[k27_of(o, 1) * NPAR + P0 + row1];
    __syncthreads();

#pragma unroll 1
    for (int s = 0; s < 8; s += 2) {
        // phase A: slot s from buf0/bA; stage slot s+1 -> buf1, B(s+1) -> bB
        stageA(Ag, nv0, nv1, zsrc, A_lds[1], base0, base1, cch);
        loadB(Wb + ((long)(s + 1) << 14), bB, wn, lane);
        if (s + 2 < 8) {
            nv0 = pidx27[k27_of(o, s + 2) * NPAR + P0 + row0];
            nv1 = pidx27[k27_of(o, s + 2) * NPAR + P0 + row1];
        }
        mfma_phase(A_lds[0], bA, acc, wm, l16, quad);
        __syncthreads();
        // phase B: slot s+1 from buf1/bB; stage slot s+2 -> buf0, B(s+2) -> bA
        if (s + 2 < 8) {
            stageA(Ag, nv0, nv1, zsrc, A_lds[0], base0, base1, cch);
            loadB(Wb + ((long)(s + 2) << 14), bA, wn, lane);
            if (s + 3 < 8) {
                nv0 = pidx27[k27_of(o, s + 3) * NPAR + P0 + row0];
                nv1 = pidx27[k27_of(o, s + 3) * NPAR + P0 + row1];
            }
        }
        mfma_phase(A_lds[1], bB, acc, wm, l16, quad);
        __syncthreads();
    }

    // ---- epilogue: coalesced bf16 store at row o*NPAR + p, fused GN2 stats
    float s_[4] = {0.f, 0.f, 0.f, 0.f}, q_[4] = {0.f, 0.f, 0.f, 0.f};
#pragma unroll
    for (int nt = 0; nt < 4; ++nt) {
        int col = wn * 64 + nt * 16 + l16;
        float bv = bias[col];
#pragma unroll
        for (int mt = 0; mt < 4; ++mt) {
#pragma unroll
            for (int r = 0; r < 4; ++r) {
                int prow = wm * 64 + mt * 16 + quad * 4 + r;
                long R = (long)o * NPAR + P0 + prow;
                float v = acc[mt][nt][r] + bv;
                unsigned short u = f2bf(v);
                outp[R * 128 + col] = u;
                float vr = bf2f(u);
                s_[nt] += vr;
                q_[nt] += vr * vr;
            }
        }
    }
    float* sred = (float*)A_lds;   // safe: loop's trailing barrier passed
    if (t < 64) sred[t] = 0.0f;
    __syncthreads();
#pragma unroll
    for (int nt = 0; nt < 4; ++nt) {
        int g = (wn * 64 + nt * 16 + l16) >> 2;
        atomicAdd(&sred[g], s_[nt]);
        atomicAdd(&sred[32 + g], q_[nt]);
    }
    __syncthreads();
    if (t < 32) { atomicAdd(&gsum[t], sred[t]); atomicAdd(&gsq[t], sred[32 + t]); }
}

// ---------------------------------------------------------------------------
// CONV2 — 2x-unrolled tap loop with ping-pong B register sets (no copies).
__global__ void __launch_bounds__(256, 2) conv2_kernel(
    const unsigned short* __restrict__ Ag, const unsigned short* __restrict__ Wp,
    const float* __restrict__ bias, const int* __restrict__ idx_tab,
    const float* __restrict__ resid, float* __restrict__ outp,
    const float* __restrict__ zpage) {
    __shared__ unsigned short A_lds[2][16384];   // 2 x 32 KB

    int t = threadIdx.x;
    int R0 = blockIdx.x * 128;
    int wv = t >> 6, lane = t & 63, quad = lane >> 4, l16 = lane & 15;
    int wm = wv & 1, wn = wv >> 1;
    int r16 = lane >> 2, cch = lane & 3;
    int c0 = wv * 2, c1 = wv * 2 + 1;
    int row0 = ((c0 >> 2) << 6) + ((c0 & 3) << 4) + r16;
    int row1 = ((c1 >> 2) << 6) + ((c1 & 3) << 4) + r16;
    int base0 = ((c0 >> 2) << 13) + ((c0 & 3) << 11);
    int base1 = ((c1 >> 2) << 13) + ((c1 & 3) << 11);
    const unsigned short* zsrc = (const unsigned short*)zpage;

    floatx4 acc[4][4];
#pragma unroll
    for (int mt = 0; mt < 4; ++mt)
#pragma unroll
        for (int nt = 0; nt < 4; ++nt)
            acc[mt][nt] = (floatx4){0.f, 0.f, 0.f, 0.f};
    short8 bA[4][4], bB[4][4];

    // ---- prolog: tap 0 A -> buf0, tap 0 B -> bA
    stageA(Ag, idx_tab[R0 + row0], idx_tab[R0 + row1], zsrc, A_lds[0], base0, base1, cch);
    loadB(Wp, bA, wn, lane);
    int nv0 = idx_tab[NCH + R0 + row0], nv1 = idx_tab[NCH + R0 + row1];
    __syncthreads();

#pragma unroll 1
    for (int k = 0; k < 27; k += 2) {
        // phase A: tap k from buf0/bA
        if (k + 1 < 27) {
            stageA(Ag, nv0, nv1, zsrc, A_lds[1], base0, base1, cch);
            loadB(Wp + ((long)(k + 1) << 14), bB, wn, lane);
            if (k + 2 < 27) {
                nv0 = idx_tab[(k + 2) * NCH + R0 + row0];
                nv1 = idx_tab[(k + 2) * NCH + R0 + row1];
            }
        }
        mfma_phase(A_lds[0], bA, acc, wm, l16, quad);
        __syncthreads();
        // phase B: tap k+1 from buf1/bB
        if (k + 1 < 27) {
            if (k + 2 < 27) {
                stageA(Ag, nv0, nv1, zsrc, A_lds[0], base0, base1, cch);
                loadB(Wp + ((long)(k + 2) << 14), bA, wn, lane);
                if (k + 3 < 27) {
                    nv0 = idx_tab[(k + 3) * NCH + R0 + row0];
                    nv1 = idx_tab[(k + 3) * NCH + R0 + row1];
                }
            }
            mfma_phase(A_lds[1], bB, acc, wm, l16, quad);
            __syncthreads();
        }
    }

#pragma unroll
    for (int nt = 0; nt < 4; ++nt) {
        int col = wn * 64 + nt * 16 + l16;
        float bv = bias[col];
#pragma unroll
        for (int mt = 0; mt < 4; ++mt) {
#pragma unroll
            for (int r = 0; r < 4; ++r) {
                int row = wm * 64 + mt * 16 + quad * 4 + r;
                long R = (long)R0 + row;
                float v = acc[mt][nt][r] + bv + resid[(R >> 3) * 128 + col];
                outp[R * 128 + col] = v;
            }
        }
    }
}

// ---------------------------------------------------------------------------
extern "C" void kernel_launch(void* const* d_in, const int* in_sizes, int n_in,
                              void* d_out, int out_size, void* d_ws, size_t ws_size,
                              hipStream_t stream) {
    const float* feats  = (const float*)d_in[0];
    const float* gamma1 = (const float*)d_in[1];
    const float* beta1  = (const float*)d_in[2];
    const float* W1     = (const float*)d_in[3];
    const float* b1     = (const float*)d_in[4];
    const float* gamma2 = (const float*)d_in[5];
    const float* beta2  = (const float*)d_in[6];
    const float* W2     = (const float*)d_in[7];
    const float* b2     = (const float*)d_in[8];
    const int*   coords = (const int*)d_in[9];
    float* out = (float*)d_out;   // 65536 x 128 fp32 (written only by conv2)

    char* ws = (char*)d_ws;
    unsigned short* h0b  = (unsigned short*)(ws);                    // 2 MB
    unsigned short* h1b  = (unsigned short*)(ws + (2u << 20));       // 16 MB, (o,p) layout
    unsigned short* Wc1f = (unsigned short*)(ws + (18u << 20));      // 2 MB
    unsigned short* Wp2  = (unsigned short*)(ws + (20u << 20));      // 864 KB
    int*   grid32        = (int*)  (ws + (21u << 20));               // 128 KB
    float* stats         = (float*)(ws + (21u << 20) + 131072);      // 512 B
    float* zpage         = (float*)(ws + (21u << 20) + 131072 + 512);// 512 B
    int*   idx_tab       = (int*)  (ws + (22u << 20));               // 7.08 MB
    int*   pidx27        = (int*)  (ws + (30u << 20));               // 864 KB

    // zero stats (128 f) + zpage (128 f) in one async memset
    hipMemsetAsync(stats, 0, 1024, stream);

    k1_kernel<<<288, 256, 0, stream>>>(coords, grid32, feats, stats + 0, stats + 32);
    k2_kernel<<<2104, 256, 0, stream>>>(coords, grid32, idx_tab, pidx27,
                                        W1, W2, Wc1f, Wp2,
                                        feats, stats + 0, stats + 32, gamma1, beta1, h0b);

    // conv1 folded -> bf16 h1b in (o,p) layout + fused GN2 stats
    conv1_fold_kernel<<<8 * (NPAR / 128), 256, 0, stream>>>(h0b, Wc1f, b1, pidx27,
                                                            h1b, zpage,
                                                            stats + 64, stats + 96);

    gn_apply_bf16_kernel<<<1024, 256, 0, stream>>>(h1b, stats + 64, stats + 96, gamma2, beta2, NCH);

    // conv2 (27 taps over children) -> fp32 out + residual repeat(feats,8)
    conv2_kernel<<<NCH / 128, 256, 0, stream>>>(h1b, Wp2, b2, idx_tab,
                                                feats, out, zpage);
}